// Round 9
// baseline (1156.665 us; speedup 1.0000x reference)
//
#include <hip/hip_runtime.h>
#include <math.h>

// B=16, L=64, H=512, N_LABELS=64, ITERS=3
//
// ws layout (float offsets):
//   wbp 0 [131072] W_ID bf16 B-fragment-major
//   v2h 131072, v2l 262144, v1h 393216, v1l 524288 [131072 each]
//   sfbuf 655360, r_slot 1179648, hid 1703936 [524288 each]
//   smat 2228224 [4096], f 2232320 [8192]
//   wia_t 2240512, wsa_t 2306048 [65536 each]

typedef __attribute__((ext_vector_type(8))) short bf16x8;
typedef __attribute__((ext_vector_type(4))) float f32x4;

__device__ inline short f2bf(float x) {  // RNE
  unsigned u = __float_as_uint(x);
  unsigned r = (u + 0x7fffu + ((u >> 16) & 1u)) >> 16;
  return (short)r;
}
__device__ inline float bf2f(short s) {
  return __uint_as_float(((unsigned)(unsigned short)s) << 16);
}
__device__ inline unsigned pack2(float a, float b) {  // truncating 2xbf16
  return (__float_as_uint(a) >> 16) | (__float_as_uint(b) & 0xffff0000u);
}
__device__ inline float ftanh(float x) {
  float t = __expf(2.f * x);
  return 1.f - 2.f * __builtin_amdgcn_rcpf(t + 1.f);
}

// ---- prep: packs + wia/wsa transposes ----
__global__ __launch_bounds__(256) void k_prep(
    const float* __restrict__ W_ID, const float* __restrict__ V2,
    const float* __restrict__ V1, const float* __restrict__ W_ia,
    const float* __restrict__ W_sa, short* __restrict__ wbp,
    short* __restrict__ v2h, short* __restrict__ v2l,
    short* __restrict__ v1h, short* __restrict__ v1l,
    float* __restrict__ wia_t, float* __restrict__ wsa_t) {
  const int bx = blockIdx.x;
  const int t = threadIdx.x;
  if (bx < 1024) {
    int idx = bx * 256 + t;  // 262144
    int j = idx & 7, lane = (idx >> 3) & 63;
    int ntile = (idx >> 9) & 31, kstep = idx >> 14;
    int g = ntile * 16 + (lane & 15);
    int h = kstep * 32 + (lane >> 4) * 8 + j;
    int src = g * 512 + h;
    wbp[idx] = f2bf(W_ID[src]);
    float x2 = V2[src];
    short h2 = f2bf(x2);
    v2h[idx] = h2;
    v2l[idx] = f2bf(x2 - bf2f(h2));
    float x1 = V1[src];
    short h1 = f2bf(x1);
    v1h[idx] = h1;
    v1l[idx] = f2bf(x1 - bf2f(h1));
  } else {
    const float* tin;
    float* tout;
    int c0;
    if (bx < 1040) { tin = W_ia; tout = wia_t; c0 = (bx - 1024) * 64; }
    else           { tin = W_sa; tout = wsa_t; c0 = (bx - 1040) * 64; }
    __shared__ float tile[64][65];
    const int tx = t & 63, ty = t >> 6;
#pragma unroll
    for (int it2 = 0; it2 < 16; ++it2) {
      int rl = ty + it2 * 4;
      tile[rl][tx] = tin[rl * 1024 + c0 + tx];
    }
    __syncthreads();
#pragma unroll
    for (int it2 = 0; it2 < 16; ++it2) {
      int cl = ty + it2 * 4;
      tout[(c0 + cl) * 64 + tx] = tile[tx][cl];
    }
  }
}

// ---- split-precision MFMA linear: C[M,512] = A[M,512] @ W[512,512]^T (+bias)
// mode0 (f==null): A read directly.  mode1 (f!=null): A = f[b,:] (x) c_slot,
// and nh==0 blocks write r_slot rows as a side effect.
__global__ __launch_bounds__(256) void k_lin(const float* __restrict__ A,
                                             const float* __restrict__ c_slot,
                                             const float* __restrict__ f,
                                             const short* __restrict__ bh,
                                             const short* __restrict__ bl,
                                             const float* __restrict__ bias,
                                             float* __restrict__ C,
                                             float* __restrict__ rs_out,
                                             float* __restrict__ smat0,
                                             float* __restrict__ fzero) {
  __shared__ short Ah[2][512], Al[2][512];
  __shared__ float fl[512];
  const int m0 = blockIdx.x * 16;
  const int nh = blockIdx.y;
  const int t = threadIdx.x;
  if (smat0 && nh == 0 && blockIdx.x < 8) {
    smat0[blockIdx.x * 512 + t] = 0.f;
    smat0[blockIdx.x * 512 + 256 + t] = 0.f;
  }
  if (fzero && nh == 1 && blockIdx.x < 16) {
    fzero[blockIdx.x * 512 + t] = 0.f;
    fzero[blockIdx.x * 512 + 256 + t] = 0.f;
  }
  if (f) {
    fl[t] = f[(blockIdx.x >> 2) * 512 + t];
    fl[t + 256] = f[(blockIdx.x >> 2) * 512 + 256 + t];
  }
  const int w = t >> 6, lane = t & 63;
  const int lq = lane >> 4, lm = lane & 15;
  f32x4 acc[4];
#pragma unroll
  for (int c = 0; c < 4; ++c) acc[c] = (f32x4){0.f, 0.f, 0.f, 0.f};

  const bf16x8* gbh = (const bf16x8*)bh + (nh * 16 + w * 4) * 64 + lane;
  const bf16x8* gbl = (const bf16x8*)bl + (nh * 16 + w * 4) * 64 + lane;

  const int la = t >> 2, j0 = (t & 3) * 2;
  const int m = la & 15, kk = (la >> 4) * 8 + j0;
  const float* abase = (f ? c_slot : A) + (m0 + m) * 512 + kk;
  float* rbase = rs_out + (m0 + m) * 512 + kk;
  if (f) __syncthreads();
  float2 x = *(const float2*)abase;

  for (int ks = 0; ks < 16; ++ks) {
    const int buf = ks & 1;
    bf16x8 b0h = gbh[ks * 2048];
    bf16x8 b1h = gbh[ks * 2048 + 64];
    bf16x8 b2h = gbh[ks * 2048 + 128];
    bf16x8 b3h = gbh[ks * 2048 + 192];
    bf16x8 b0l = gbl[ks * 2048];
    bf16x8 b1l = gbl[ks * 2048 + 64];
    bf16x8 b2l = gbl[ks * 2048 + 128];
    bf16x8 b3l = gbl[ks * 2048 + 192];
    float2 xn = x;
    if (ks < 15) xn = *(const float2*)(abase + (ks + 1) * 32);
    float a0 = x.x, a1 = x.y;
    if (f) {
      a0 *= fl[ks * 32 + kk];
      a1 *= fl[ks * 32 + kk + 1];
      if (nh == 0) *(float2*)(rbase + ks * 32) = make_float2(a0, a1);
    }
    short h0 = f2bf(a0), h1 = f2bf(a1);
    short l0 = f2bf(a0 - bf2f(h0)), l1 = f2bf(a1 - bf2f(h1));
    *(short2*)&Ah[buf][t * 2] = make_short2(h0, h1);
    *(short2*)&Al[buf][t * 2] = make_short2(l0, l1);
    __syncthreads();
    bf16x8 ah = *(const bf16x8*)&Ah[buf][lane * 8];
    bf16x8 al = *(const bf16x8*)&Al[buf][lane * 8];
    acc[0] = __builtin_amdgcn_mfma_f32_16x16x32_bf16(ah, b0h, acc[0], 0, 0, 0);
    acc[0] = __builtin_amdgcn_mfma_f32_16x16x32_bf16(al, b0h, acc[0], 0, 0, 0);
    acc[0] = __builtin_amdgcn_mfma_f32_16x16x32_bf16(ah, b0l, acc[0], 0, 0, 0);
    acc[1] = __builtin_amdgcn_mfma_f32_16x16x32_bf16(ah, b1h, acc[1], 0, 0, 0);
    acc[1] = __builtin_amdgcn_mfma_f32_16x16x32_bf16(al, b1h, acc[1], 0, 0, 0);
    acc[1] = __builtin_amdgcn_mfma_f32_16x16x32_bf16(ah, b1l, acc[1], 0, 0, 0);
    acc[2] = __builtin_amdgcn_mfma_f32_16x16x32_bf16(ah, b2h, acc[2], 0, 0, 0);
    acc[2] = __builtin_amdgcn_mfma_f32_16x16x32_bf16(al, b2h, acc[2], 0, 0, 0);
    acc[2] = __builtin_amdgcn_mfma_f32_16x16x32_bf16(ah, b2l, acc[2], 0, 0, 0);
    acc[3] = __builtin_amdgcn_mfma_f32_16x16x32_bf16(ah, b3h, acc[3], 0, 0, 0);
    acc[3] = __builtin_amdgcn_mfma_f32_16x16x32_bf16(al, b3h, acc[3], 0, 0, 0);
    acc[3] = __builtin_amdgcn_mfma_f32_16x16x32_bf16(ah, b3l, acc[3], 0, 0, 0);
    x = xn;
  }
#pragma unroll
  for (int c = 0; c < 4; ++c)
#pragma unroll
    for (int reg = 0; reg < 4; ++reg) {
      int mm = m0 + lq * 4 + reg;
      int n = nh * 256 + (w * 4 + c) * 16 + lm;
      float v = acc[c][reg];
      if (bias) v += bias[n];
      C[mm * 512 + n] = v;
    }
}

// ---- per-iteration mid chain (unchanged) ----
__global__ __launch_bounds__(512) void k_mid(int first,
                                             const float* __restrict__ smat,
                                             const float* __restrict__ r_slot,
                                             const float* __restrict__ c_inte,
                                             const float* __restrict__ c_slot,
                                             const float* __restrict__ W_SF,
                                             const float* __restrict__ V_SF,
                                             float* __restrict__ f) {
  __shared__ float av[64];
  __shared__ float rl[512];
  __shared__ float red[512];
  __shared__ float tm[128];
  __shared__ float ts[128];
  const int b = blockIdx.x >> 2, q = blockIdx.x & 3;
  const int t = threadIdx.x;

  if (first) {
    rl[t] = c_inte[b * 512 + t];
    __syncthreads();
  } else {
    if (t < 256) {
      int w = t >> 6, lane = t & 63;
      for (int r = w * 16; r < w * 16 + 16; ++r) {
        float v = smat[r * 64 + lane];
        float s = v;
        s += __shfl_xor(s, 1);
        s += __shfl_xor(s, 2);
        s += __shfl_xor(s, 4);
        s += __shfl_xor(s, 8);
        s += __shfl_xor(s, 16);
        s += __shfl_xor(s, 32);
        float d = __shfl(v, r);
        if (lane == 0) av[r] = d / s;
      }
    }
    __syncthreads();
    float a = 0.f;
    const float* rp = r_slot + b * 64 * 512 + t;
#pragma unroll 8
    for (int i = 0; i < 64; ++i) a += av[i] * rp[i * 512];
    rl[t] = a + c_inte[b * 512 + t];
    __syncthreads();
  }

  {
    const int hh = q * 128 + (t >> 2), kq = t & 3;
    const float* wr = W_SF + hh * 512 + kq * 128;
    const float* rv = rl + kq * 128;
    float p = 0.f;
    for (int k = 0; k < 128; k += 4) {
      float4 wv = *(const float4*)(wr + k);
      p += rv[k] * wv.x + rv[k + 1] * wv.y + rv[k + 2] * wv.z + rv[k + 3] * wv.w;
    }
    red[t] = p;
  }
  __syncthreads();
  if (t < 128) tm[t] = red[t * 4] + red[t * 4 + 1] + red[t * 4 + 2] + red[t * 4 + 3];
  __syncthreads();
  {
    const int hh = q * 128 + (t >> 2), lc = t & 3;
    float tmp_h = tm[t >> 2];
    const float* cp = c_slot + (b * 64 + lc * 16) * 512 + hh;
    float s = 0.f;
    for (int l = 0; l < 16; ++l) s += ftanh(cp[l * 512] + tmp_h);
    red[t] = s;
  }
  __syncthreads();
  if (t < 128) ts[t] = red[t * 4] + red[t * 4 + 1] + red[t * 4 + 2] + red[t * 4 + 3];
  __syncthreads();
  {
    const float* vr = V_SF + t * 512 + q * 128;
    float p = 0.f;
    for (int k = 0; k < 128; k += 4) {
      float4 vv = *(const float4*)(vr + k);
      p += ts[k] * vv.x + ts[k + 1] * vv.y + ts[k + 2] * vv.z + ts[k + 3] * vv.w;
    }
    atomicAdd(&f[b * 512 + t], p);
  }
}

// ---- dominant kernel v5: 2 i-rows per block, B fragments reused ----
// grid (32 i-pairs, 16 b); 512 thr = 8 waves; wave w owns ntiles w*4..w*4+3.
__global__ __launch_bounds__(512, 4) void k_score(const float* __restrict__ hid,
                                                  const float* __restrict__ sf,
                                                  const short* __restrict__ wbp,
                                                  float* __restrict__ smat,
                                                  float* __restrict__ fz,
                                                  float* __restrict__ oz) {
  __shared__ short As[2][2][2048];  // [buf][ii][frag] 16 KB
  __shared__ float red[8][64];
  const int ip = blockIdx.x, b = blockIdx.y;
  const int t = threadIdx.x;
  if (fz && ip == 0) fz[b * 512 + t] = 0.f;
  if (oz && ip == 1 && b < 2) oz[b * 512 + t] = 0.f;
  const int w = t >> 6, lane = t & 63;
  const int lq = lane >> 4, lm = lane & 15;

  f32x4 acc[2][4][4];
#pragma unroll
  for (int ii = 0; ii < 2; ++ii)
#pragma unroll
    for (int r = 0; r < 4; ++r)
#pragma unroll
      for (int c = 0; c < 4; ++c) acc[ii][r][c] = (f32x4){0.f, 0.f, 0.f, 0.f};

  const float* hrow0 = hid + (b * 64 + ip * 2) * 512;
  const float* hrow1 = hrow0 + 512;
  const float* sfb = sf + b * 64 * 512;

  const int fid = t >> 1, half = t & 1;
  const int am = (fid >> 6) * 16 + (fid & 15);
  const int ak = ((fid >> 4) & 3) * 8 + half * 4;
  const int aoff = fid * 8 + half * 4;

  const bf16x8* gb = (const bf16x8*)wbp + (w * 4) * 64 + lane;
  const float* hp0 = hrow0 + ak;
  const float* hp1 = hrow1 + ak;
  const float* sp0 = sfb + am * 512 + ak;
  float4 hv0 = *(const float4*)hp0;
  float4 hv1 = *(const float4*)hp1;
  float4 sv = *(const float4*)sp0;

  for (int ks = 0; ks < 16; ++ks) {
    const int buf = ks & 1;
    bf16x8 b0 = gb[ks * 2048];
    bf16x8 b1 = gb[ks * 2048 + 64];
    bf16x8 b2 = gb[ks * 2048 + 128];
    bf16x8 b3 = gb[ks * 2048 + 192];
    float4 h0n = hv0, h1n = hv1, svn = sv;
    if (ks < 15) {
      h0n = *(const float4*)(hp0 + (ks + 1) * 32);
      h1n = *(const float4*)(hp1 + (ks + 1) * 32);
      svn = *(const float4*)(sp0 + (ks + 1) * 32);
    }
    {
      uint2 pk;
      pk.x = pack2(ftanh(hv0.x + sv.x), ftanh(hv0.y + sv.y));
      pk.y = pack2(ftanh(hv0.z + sv.z), ftanh(hv0.w + sv.w));
      *(uint2*)&As[buf][0][aoff] = pk;
      uint2 pk2;
      pk2.x = pack2(ftanh(hv1.x + sv.x), ftanh(hv1.y + sv.y));
      pk2.y = pack2(ftanh(hv1.z + sv.z), ftanh(hv1.w + sv.w));
      *(uint2*)&As[buf][1][aoff] = pk2;
    }
    __syncthreads();
#pragma unroll
    for (int ii = 0; ii < 2; ++ii) {
      bf16x8 af0 = *(const bf16x8*)&As[buf][ii][(0 * 64 + lane) * 8];
      bf16x8 af1 = *(const bf16x8*)&As[buf][ii][(1 * 64 + lane) * 8];
      bf16x8 af2 = *(const bf16x8*)&As[buf][ii][(2 * 64 + lane) * 8];
      bf16x8 af3 = *(const bf16x8*)&As[buf][ii][(3 * 64 + lane) * 8];
      acc[ii][0][0] = __builtin_amdgcn_mfma_f32_16x16x32_bf16(af0, b0, acc[ii][0][0], 0, 0, 0);
      acc[ii][1][0] = __builtin_amdgcn_mfma_f32_16x16x32_bf16(af1, b0, acc[ii][1][0], 0, 0, 0);
      acc[ii][2][0] = __builtin_amdgcn_mfma_f32_16x16x32_bf16(af2, b0, acc[ii][2][0], 0, 0, 0);
      acc[ii][3][0] = __builtin_amdgcn_mfma_f32_16x16x32_bf16(af3, b0, acc[ii][3][0], 0, 0, 0);
      acc[ii][0][1] = __builtin_amdgcn_mfma_f32_16x16x32_bf16(af0, b1, acc[ii][0][1], 0, 0, 0);
      acc[ii][1][1] = __builtin_amdgcn_mfma_f32_16x16x32_bf16(af1, b1, acc[ii][1][1], 0, 0, 0);
      acc[ii][2][1] = __builtin_amdgcn_mfma_f32_16x16x32_bf16(af2, b1, acc[ii][2][1], 0, 0, 0);
      acc[ii][3][1] = __builtin_amdgcn_mfma_f32_16x16x32_bf16(af3, b1, acc[ii][3][1], 0, 0, 0);
      acc[ii][0][2] = __builtin_amdgcn_mfma_f32_16x16x32_bf16(af0, b2, acc[ii][0][2], 0, 0, 0);
      acc[ii][1][2] = __builtin_amdgcn_mfma_f32_16x16x32_bf16(af1, b2, acc[ii][1][2], 0, 0, 0);
      acc[ii][2][2] = __builtin_amdgcn_mfma_f32_16x16x32_bf16(af2, b2, acc[ii][2][2], 0, 0, 0);
      acc[ii][3][2] = __builtin_amdgcn_mfma_f32_16x16x32_bf16(af3, b2, acc[ii][3][2], 0, 0, 0);
      acc[ii][0][3] = __builtin_amdgcn_mfma_f32_16x16x32_bf16(af0, b3, acc[ii][0][3], 0, 0, 0);
      acc[ii][1][3] = __builtin_amdgcn_mfma_f32_16x16x32_bf16(af1, b3, acc[ii][1][3], 0, 0, 0);
      acc[ii][2][3] = __builtin_amdgcn_mfma_f32_16x16x32_bf16(af2, b3, acc[ii][2][3], 0, 0, 0);
      acc[ii][3][3] = __builtin_amdgcn_mfma_f32_16x16x32_bf16(af3, b3, acc[ii][3][3], 0, 0, 0);
    }
    hv0 = h0n;
    hv1 = h1n;
    sv = svn;
  }

#pragma unroll
  for (int ii = 0; ii < 2; ++ii) {
#pragma unroll
    for (int r = 0; r < 4; ++r) {
#pragma unroll
      for (int reg = 0; reg < 4; ++reg) {
        float v = __expf(acc[ii][r][0][reg]) + __expf(acc[ii][r][1][reg]) +
                  __expf(acc[ii][r][2][reg]) + __expf(acc[ii][r][3][reg]);
        v += __shfl_down(v, 8, 16);
        v += __shfl_down(v, 4, 16);
        v += __shfl_down(v, 2, 16);
        v += __shfl_down(v, 1, 16);
        if (lm == 0) red[w][r * 16 + lq * 4 + reg] = v;
      }
    }
    __syncthreads();
    if (t < 64) {
      float s = 0.f;
#pragma unroll
      for (int ww = 0; ww < 8; ++ww) s += red[ww][t];
      atomicAdd(&smat[(ip * 2 + ii) * 64 + t], s);
    }
    __syncthreads();
  }
}

// ---- final: atts + riv chunk + intent partials (atomic). grid 128, 256 thr
__global__ __launch_bounds__(256) void k_fin(const float* __restrict__ smat,
                                             const float* __restrict__ r_slot,
                                             const float* __restrict__ c_inte,
                                             const float* __restrict__ h,
                                             const float* __restrict__ wia_t,
                                             float* __restrict__ out) {
  __shared__ float av[64], riv[64], red[256];
  const int b = blockIdx.x >> 3, kc = blockIdx.x & 7;
  const int t = threadIdx.x;
  const int w = t >> 6, lane = t & 63;
  for (int r = w * 16; r < w * 16 + 16; ++r) {
    float v = smat[r * 64 + lane];
    float s = v;
    s += __shfl_xor(s, 1);
    s += __shfl_xor(s, 2);
    s += __shfl_xor(s, 4);
    s += __shfl_xor(s, 8);
    s += __shfl_xor(s, 16);
    s += __shfl_xor(s, 32);
    float d = __shfl(v, r);
    if (lane == 0) av[r] = d / s;
  }
  __syncthreads();
  {
    const int hh = kc * 64 + lane;
    float a = 0.f;
    const float* rp = r_slot + (b * 64 + w * 16) * 512 + hh;
#pragma unroll
    for (int i = 0; i < 16; ++i) a += av[w * 16 + i] * rp[i * 512];
    red[t] = a;
  }
  __syncthreads();
  if (t < 64)
    riv[t] = red[t] + red[t + 64] + red[t + 128] + red[t + 192] +
             c_inte[b * 512 + kc * 64 + t];
  __syncthreads();
  {
    const int n = lane;
    const float* hrow = h + (b * 64 + 63) * 512 + kc * 64;
    float p = 0.f;
#pragma unroll
    for (int k = w * 16; k < w * 16 + 16; ++k) {
      p += riv[k] * wia_t[(kc * 64 + k) * 64 + n];
      p += hrow[k] * wia_t[(512 + kc * 64 + k) * 64 + n];
    }
    red[t] = p;
  }
  __syncthreads();
  if (t < 64)
    atomicAdd(&out[b * 64 + t], red[t] + red[t + 64] + red[t + 128] + red[t + 192]);
}

// slot[(b,l),n] = [h[b,l], r_slot[b,l]] @ W_sa[n,:]  via wsa_t
__global__ __launch_bounds__(256) void k_slot(const float* __restrict__ h,
                                              const float* __restrict__ r_slot,
                                              const float* __restrict__ wsa_t,
                                              float* __restrict__ out) {
  int idx = blockIdx.x * 256 + threadIdx.x;  // 65536
  int ml = idx >> 6, n = idx & 63;
  const float* x1 = h + ml * 512;
  const float* x2 = r_slot + ml * 512;
  float acc = 0.f;
  for (int k = 0; k < 512; k += 4) {
    float4 x = *(const float4*)(x1 + k);
    acc += x.x * wsa_t[k * 64 + n] + x.y * wsa_t[(k + 1) * 64 + n] +
           x.z * wsa_t[(k + 2) * 64 + n] + x.w * wsa_t[(k + 3) * 64 + n];
  }
  for (int k = 0; k < 512; k += 4) {
    float4 x = *(const float4*)(x2 + k);
    acc += x.x * wsa_t[(512 + k) * 64 + n] + x.y * wsa_t[(513 + k) * 64 + n] +
           x.z * wsa_t[(514 + k) * 64 + n] + x.w * wsa_t[(515 + k) * 64 + n];
  }
  out[idx] = acc;
}

extern "C" void kernel_launch(void* const* d_in, const int* in_sizes, int n_in,
                              void* d_out, int out_size, void* d_ws, size_t ws_size,
                              hipStream_t stream) {
  const float* h      = (const float*)d_in[0];
  const float* c_slot = (const float*)d_in[1];
  const float* c_inte = (const float*)d_in[2];
  const float* W_SF   = (const float*)d_in[3];
  const float* V_SF   = (const float*)d_in[4];
  const float* V1_ID  = (const float*)d_in[5];
  const float* V2_w   = (const float*)d_in[6];
  const float* V2_b   = (const float*)d_in[7];
  const float* W_ID   = (const float*)d_in[8];
  const float* W_ia   = (const float*)d_in[9];
  const float* W_sa   = (const float*)d_in[10];
  float* out = (float*)d_out;

  float* ws     = (float*)d_ws;
  short* wbp    = (short*)ws;
  short* v2h    = (short*)(ws + 131072);
  short* v2l    = (short*)(ws + 262144);
  short* v1h    = (short*)(ws + 393216);
  short* v1l    = (short*)(ws + 524288);
  float* sfbuf  = ws + 655360;
  float* r_slot = ws + 1179648;
  float* hid    = ws + 1703936;
  float* smat   = ws + 2228224;
  float* f      = ws + 2232320;
  float* wia_t  = ws + 2240512;
  float* wsa_t  = ws + 2306048;

  k_prep<<<1056, 256, 0, stream>>>(W_ID, V2_w, V1_ID, W_ia, W_sa,
                                   wbp, v2h, v2l, v1h, v1l, wia_t, wsa_t);
  k_lin<<<dim3(64, 2), 256, 0, stream>>>(h, nullptr, nullptr, v2h, v2l, V2_b,
                                         sfbuf, r_slot, nullptr, f);

  for (int it = 0; it < 3; ++it) {
    k_mid<<<64, 512, 0, stream>>>(it == 0 ? 1 : 0, smat, r_slot, c_inte,
                                  c_slot, W_SF, V_SF, f);
    k_lin<<<dim3(64, 2), 256, 0, stream>>>(nullptr, c_slot, f, v1h, v1l,
                                           nullptr, hid, r_slot, smat, nullptr);
    k_score<<<dim3(32, 16), 512, 0, stream>>>(hid, sfbuf, wbp, smat, f,
                                              it == 2 ? out : nullptr);
  }

  k_fin<<<128, 256, 0, stream>>>(smat, r_slot, c_inte, h, wia_t, out);
  k_slot<<<256, 256, 0, stream>>>(h, r_slot, wsa_t, out + 1024);
}

// Round 10
// 370.373 us; speedup vs baseline: 3.1230x; 3.1230x over previous
//
#include <hip/hip_runtime.h>
#include <math.h>

// B=16, L=64, H=512, N_LABELS=64, ITERS=3
//
// ws layout (float offsets):
//   wbp 0 [131072] W_ID bf16 B-fragment-major
//   v2h 131072, v2l 262144, v1h 393216, v1l 524288 [131072 each]
//   sfbuf 655360, r_slot 1179648, hid 1703936 [524288 each]
//   smat 2228224 [4096], f 2232320 [8192]
//   wia_t 2240512, wsa_t 2306048 [65536 each]

typedef __attribute__((ext_vector_type(8))) short bf16x8;
typedef __attribute__((ext_vector_type(4))) float f32x4;

__device__ inline short f2bf(float x) {  // RNE
  unsigned u = __float_as_uint(x);
  unsigned r = (u + 0x7fffu + ((u >> 16) & 1u)) >> 16;
  return (short)r;
}
__device__ inline float bf2f(short s) {
  return __uint_as_float(((unsigned)(unsigned short)s) << 16);
}
__device__ inline unsigned pack2(float a, float b) {  // truncating 2xbf16
  return (__float_as_uint(a) >> 16) | (__float_as_uint(b) & 0xffff0000u);
}
__device__ inline float ftanh(float x) {
  float t = __expf(2.f * x);
  return 1.f - 2.f * __builtin_amdgcn_rcpf(t + 1.f);
}

// ---- prep: packs + wia/wsa transposes ----
__global__ __launch_bounds__(256) void k_prep(
    const float* __restrict__ W_ID, const float* __restrict__ V2,
    const float* __restrict__ V1, const float* __restrict__ W_ia,
    const float* __restrict__ W_sa, short* __restrict__ wbp,
    short* __restrict__ v2h, short* __restrict__ v2l,
    short* __restrict__ v1h, short* __restrict__ v1l,
    float* __restrict__ wia_t, float* __restrict__ wsa_t) {
  const int bx = blockIdx.x;
  const int t = threadIdx.x;
  if (bx < 1024) {
    int idx = bx * 256 + t;  // 262144
    int j = idx & 7, lane = (idx >> 3) & 63;
    int ntile = (idx >> 9) & 31, kstep = idx >> 14;
    int g = ntile * 16 + (lane & 15);
    int h = kstep * 32 + (lane >> 4) * 8 + j;
    int src = g * 512 + h;
    wbp[idx] = f2bf(W_ID[src]);
    float x2 = V2[src];
    short h2 = f2bf(x2);
    v2h[idx] = h2;
    v2l[idx] = f2bf(x2 - bf2f(h2));
    float x1 = V1[src];
    short h1 = f2bf(x1);
    v1h[idx] = h1;
    v1l[idx] = f2bf(x1 - bf2f(h1));
  } else {
    const float* tin;
    float* tout;
    int c0;
    if (bx < 1040) { tin = W_ia; tout = wia_t; c0 = (bx - 1024) * 64; }
    else           { tin = W_sa; tout = wsa_t; c0 = (bx - 1040) * 64; }
    __shared__ float tile[64][65];
    const int tx = t & 63, ty = t >> 6;
#pragma unroll
    for (int it2 = 0; it2 < 16; ++it2) {
      int rl = ty + it2 * 4;
      tile[rl][tx] = tin[rl * 1024 + c0 + tx];
    }
    __syncthreads();
#pragma unroll
    for (int it2 = 0; it2 < 16; ++it2) {
      int cl = ty + it2 * 4;
      tout[(c0 + cl) * 64 + tx] = tile[tx][cl];
    }
  }
}

// ---- split-precision MFMA linear: C[M,512] = A[M,512] @ W[512,512]^T (+bias)
// mode0 (f==null): A read directly.  mode1 (f!=null): A = f[b,:] (x) c_slot,
// and nh==0 blocks write r_slot rows as a side effect.
__global__ __launch_bounds__(256) void k_lin(const float* __restrict__ A,
                                             const float* __restrict__ c_slot,
                                             const float* __restrict__ f,
                                             const short* __restrict__ bh,
                                             const short* __restrict__ bl,
                                             const float* __restrict__ bias,
                                             float* __restrict__ C,
                                             float* __restrict__ rs_out,
                                             float* __restrict__ smat0,
                                             float* __restrict__ fzero) {
  __shared__ short Ah[2][512], Al[2][512];
  __shared__ float fl[512];
  const int m0 = blockIdx.x * 16;
  const int nh = blockIdx.y;
  const int t = threadIdx.x;
  if (smat0 && nh == 0 && blockIdx.x < 8) {
    smat0[blockIdx.x * 512 + t] = 0.f;
    smat0[blockIdx.x * 512 + 256 + t] = 0.f;
  }
  if (fzero && nh == 1 && blockIdx.x < 16) {
    fzero[blockIdx.x * 512 + t] = 0.f;
    fzero[blockIdx.x * 512 + 256 + t] = 0.f;
  }
  if (f) {
    fl[t] = f[(blockIdx.x >> 2) * 512 + t];
    fl[t + 256] = f[(blockIdx.x >> 2) * 512 + 256 + t];
  }
  const int w = t >> 6, lane = t & 63;
  const int lq = lane >> 4, lm = lane & 15;
  f32x4 acc[4];
#pragma unroll
  for (int c = 0; c < 4; ++c) acc[c] = (f32x4){0.f, 0.f, 0.f, 0.f};

  const bf16x8* gbh = (const bf16x8*)bh + (nh * 16 + w * 4) * 64 + lane;
  const bf16x8* gbl = (const bf16x8*)bl + (nh * 16 + w * 4) * 64 + lane;

  const int la = t >> 2, j0 = (t & 3) * 2;
  const int m = la & 15, kk = (la >> 4) * 8 + j0;
  const float* abase = (f ? c_slot : A) + (m0 + m) * 512 + kk;
  float* rbase = rs_out + (m0 + m) * 512 + kk;
  if (f) __syncthreads();
  float2 x = *(const float2*)abase;

  for (int ks = 0; ks < 16; ++ks) {
    const int buf = ks & 1;
    bf16x8 b0h = gbh[ks * 2048];
    bf16x8 b1h = gbh[ks * 2048 + 64];
    bf16x8 b2h = gbh[ks * 2048 + 128];
    bf16x8 b3h = gbh[ks * 2048 + 192];
    bf16x8 b0l = gbl[ks * 2048];
    bf16x8 b1l = gbl[ks * 2048 + 64];
    bf16x8 b2l = gbl[ks * 2048 + 128];
    bf16x8 b3l = gbl[ks * 2048 + 192];
    float2 xn = x;
    if (ks < 15) xn = *(const float2*)(abase + (ks + 1) * 32);
    float a0 = x.x, a1 = x.y;
    if (f) {
      a0 *= fl[ks * 32 + kk];
      a1 *= fl[ks * 32 + kk + 1];
      if (nh == 0) *(float2*)(rbase + ks * 32) = make_float2(a0, a1);
    }
    short h0 = f2bf(a0), h1 = f2bf(a1);
    short l0 = f2bf(a0 - bf2f(h0)), l1 = f2bf(a1 - bf2f(h1));
    *(short2*)&Ah[buf][t * 2] = make_short2(h0, h1);
    *(short2*)&Al[buf][t * 2] = make_short2(l0, l1);
    __syncthreads();
    bf16x8 ah = *(const bf16x8*)&Ah[buf][lane * 8];
    bf16x8 al = *(const bf16x8*)&Al[buf][lane * 8];
    acc[0] = __builtin_amdgcn_mfma_f32_16x16x32_bf16(ah, b0h, acc[0], 0, 0, 0);
    acc[0] = __builtin_amdgcn_mfma_f32_16x16x32_bf16(al, b0h, acc[0], 0, 0, 0);
    acc[0] = __builtin_amdgcn_mfma_f32_16x16x32_bf16(ah, b0l, acc[0], 0, 0, 0);
    acc[1] = __builtin_amdgcn_mfma_f32_16x16x32_bf16(ah, b1h, acc[1], 0, 0, 0);
    acc[1] = __builtin_amdgcn_mfma_f32_16x16x32_bf16(al, b1h, acc[1], 0, 0, 0);
    acc[1] = __builtin_amdgcn_mfma_f32_16x16x32_bf16(ah, b1l, acc[1], 0, 0, 0);
    acc[2] = __builtin_amdgcn_mfma_f32_16x16x32_bf16(ah, b2h, acc[2], 0, 0, 0);
    acc[2] = __builtin_amdgcn_mfma_f32_16x16x32_bf16(al, b2h, acc[2], 0, 0, 0);
    acc[2] = __builtin_amdgcn_mfma_f32_16x16x32_bf16(ah, b2l, acc[2], 0, 0, 0);
    acc[3] = __builtin_amdgcn_mfma_f32_16x16x32_bf16(ah, b3h, acc[3], 0, 0, 0);
    acc[3] = __builtin_amdgcn_mfma_f32_16x16x32_bf16(al, b3h, acc[3], 0, 0, 0);
    acc[3] = __builtin_amdgcn_mfma_f32_16x16x32_bf16(ah, b3l, acc[3], 0, 0, 0);
    x = xn;
  }
#pragma unroll
  for (int c = 0; c < 4; ++c)
#pragma unroll
    for (int reg = 0; reg < 4; ++reg) {
      int mm = m0 + lq * 4 + reg;
      int n = nh * 256 + (w * 4 + c) * 16 + lm;
      float v = acc[c][reg];
      if (bias) v += bias[n];
      C[mm * 512 + n] = v;
    }
}

// ---- per-iteration mid chain (unchanged) ----
__global__ __launch_bounds__(512) void k_mid(int first,
                                             const float* __restrict__ smat,
                                             const float* __restrict__ r_slot,
                                             const float* __restrict__ c_inte,
                                             const float* __restrict__ c_slot,
                                             const float* __restrict__ W_SF,
                                             const float* __restrict__ V_SF,
                                             float* __restrict__ f) {
  __shared__ float av[64];
  __shared__ float rl[512];
  __shared__ float red[512];
  __shared__ float tm[128];
  __shared__ float ts[128];
  const int b = blockIdx.x >> 2, q = blockIdx.x & 3;
  const int t = threadIdx.x;

  if (first) {
    rl[t] = c_inte[b * 512 + t];
    __syncthreads();
  } else {
    if (t < 256) {
      int w = t >> 6, lane = t & 63;
      for (int r = w * 16; r < w * 16 + 16; ++r) {
        float v = smat[r * 64 + lane];
        float s = v;
        s += __shfl_xor(s, 1);
        s += __shfl_xor(s, 2);
        s += __shfl_xor(s, 4);
        s += __shfl_xor(s, 8);
        s += __shfl_xor(s, 16);
        s += __shfl_xor(s, 32);
        float d = __shfl(v, r);
        if (lane == 0) av[r] = d / s;
      }
    }
    __syncthreads();
    float a = 0.f;
    const float* rp = r_slot + b * 64 * 512 + t;
#pragma unroll 8
    for (int i = 0; i < 64; ++i) a += av[i] * rp[i * 512];
    rl[t] = a + c_inte[b * 512 + t];
    __syncthreads();
  }

  {
    const int hh = q * 128 + (t >> 2), kq = t & 3;
    const float* wr = W_SF + hh * 512 + kq * 128;
    const float* rv = rl + kq * 128;
    float p = 0.f;
    for (int k = 0; k < 128; k += 4) {
      float4 wv = *(const float4*)(wr + k);
      p += rv[k] * wv.x + rv[k + 1] * wv.y + rv[k + 2] * wv.z + rv[k + 3] * wv.w;
    }
    red[t] = p;
  }
  __syncthreads();
  if (t < 128) tm[t] = red[t * 4] + red[t * 4 + 1] + red[t * 4 + 2] + red[t * 4 + 3];
  __syncthreads();
  {
    const int hh = q * 128 + (t >> 2), lc = t & 3;
    float tmp_h = tm[t >> 2];
    const float* cp = c_slot + (b * 64 + lc * 16) * 512 + hh;
    float s = 0.f;
    for (int l = 0; l < 16; ++l) s += ftanh(cp[l * 512] + tmp_h);
    red[t] = s;
  }
  __syncthreads();
  if (t < 128) ts[t] = red[t * 4] + red[t * 4 + 1] + red[t * 4 + 2] + red[t * 4 + 3];
  __syncthreads();
  {
    const float* vr = V_SF + t * 512 + q * 128;
    float p = 0.f;
    for (int k = 0; k < 128; k += 4) {
      float4 vv = *(const float4*)(vr + k);
      p += ts[k] * vv.x + ts[k + 1] * vv.y + ts[k + 2] * vv.z + ts[k + 3] * vv.w;
    }
    atomicAdd(&f[b * 512 + t], p);
  }
}

// ---- dominant kernel v6: single i-row (round-8 structure, no spill),
// K-tile 64 = two 32-k slices per barrier (8 barriers instead of 16).
// grid (64 i, 16 b); 512 thr = 8 waves; wave w owns ntiles w*4..w*4+3.
__global__ __launch_bounds__(512, 4) void k_score(const float* __restrict__ hid,
                                                  const float* __restrict__ sf,
                                                  const short* __restrict__ wbp,
                                                  float* __restrict__ smat,
                                                  float* __restrict__ fz,
                                                  float* __restrict__ oz) {
  __shared__ short As[2][4096];  // [buf][slice*2048 + frag] 16 KB
  __shared__ float red[8][64];
  const int i = blockIdx.x, b = blockIdx.y;
  const int t = threadIdx.x;
  if (fz && i == 0) fz[b * 512 + t] = 0.f;
  if (oz && i == 1 && b < 2) oz[b * 512 + t] = 0.f;
  const int w = t >> 6, lane = t & 63;
  const int lq = lane >> 4, lm = lane & 15;

  f32x4 acc[4][4];
#pragma unroll
  for (int r = 0; r < 4; ++r)
#pragma unroll
    for (int c = 0; c < 4; ++c) acc[r][c] = (f32x4){0.f, 0.f, 0.f, 0.f};

  const float* hrow = hid + (b * 64 + i) * 512;
  const float* sfb = sf + b * 64 * 512;

  const int fid = t >> 1, half = t & 1;
  const int am = (fid >> 6) * 16 + (fid & 15);      // j row staged
  const int ak = ((fid >> 4) & 3) * 8 + half * 4;   // k offset in 32-k slice
  const int aoff = fid * 8 + half * 4;

  const bf16x8* gb = (const bf16x8*)wbp + (w * 4) * 64 + lane;
  const float* hp0 = hrow + ak;
  const float* sp0 = sfb + am * 512 + ak;

  for (int ks2 = 0; ks2 < 8; ++ks2) {
    const int buf = ks2 & 1;
    // stage two 32-k slices of A (tanh -> bf16, fragment order)
#pragma unroll
    for (int s = 0; s < 2; ++s) {
      const int ko = (ks2 * 2 + s) * 32;
      float4 hv = *(const float4*)(hp0 + ko);
      float4 sv = *(const float4*)(sp0 + ko);
      uint2 pk;
      pk.x = pack2(ftanh(hv.x + sv.x), ftanh(hv.y + sv.y));
      pk.y = pack2(ftanh(hv.z + sv.z), ftanh(hv.w + sv.w));
      *(uint2*)&As[buf][s * 2048 + aoff] = pk;
    }
    __syncthreads();
#pragma unroll
    for (int s = 0; s < 2; ++s) {
      const int ks = ks2 * 2 + s;
      bf16x8 b0 = gb[ks * 2048];
      bf16x8 b1 = gb[ks * 2048 + 64];
      bf16x8 b2 = gb[ks * 2048 + 128];
      bf16x8 b3 = gb[ks * 2048 + 192];
      bf16x8 af0 = *(const bf16x8*)&As[buf][s * 2048 + (0 * 64 + lane) * 8];
      bf16x8 af1 = *(const bf16x8*)&As[buf][s * 2048 + (1 * 64 + lane) * 8];
      bf16x8 af2 = *(const bf16x8*)&As[buf][s * 2048 + (2 * 64 + lane) * 8];
      bf16x8 af3 = *(const bf16x8*)&As[buf][s * 2048 + (3 * 64 + lane) * 8];
      acc[0][0] = __builtin_amdgcn_mfma_f32_16x16x32_bf16(af0, b0, acc[0][0], 0, 0, 0);
      acc[1][0] = __builtin_amdgcn_mfma_f32_16x16x32_bf16(af1, b0, acc[1][0], 0, 0, 0);
      acc[2][0] = __builtin_amdgcn_mfma_f32_16x16x32_bf16(af2, b0, acc[2][0], 0, 0, 0);
      acc[3][0] = __builtin_amdgcn_mfma_f32_16x16x32_bf16(af3, b0, acc[3][0], 0, 0, 0);
      acc[0][1] = __builtin_amdgcn_mfma_f32_16x16x32_bf16(af0, b1, acc[0][1], 0, 0, 0);
      acc[1][1] = __builtin_amdgcn_mfma_f32_16x16x32_bf16(af1, b1, acc[1][1], 0, 0, 0);
      acc[2][1] = __builtin_amdgcn_mfma_f32_16x16x32_bf16(af2, b1, acc[2][1], 0, 0, 0);
      acc[3][1] = __builtin_amdgcn_mfma_f32_16x16x32_bf16(af3, b1, acc[3][1], 0, 0, 0);
      acc[0][2] = __builtin_amdgcn_mfma_f32_16x16x32_bf16(af0, b2, acc[0][2], 0, 0, 0);
      acc[1][2] = __builtin_amdgcn_mfma_f32_16x16x32_bf16(af1, b2, acc[1][2], 0, 0, 0);
      acc[2][2] = __builtin_amdgcn_mfma_f32_16x16x32_bf16(af2, b2, acc[2][2], 0, 0, 0);
      acc[3][2] = __builtin_amdgcn_mfma_f32_16x16x32_bf16(af3, b2, acc[3][2], 0, 0, 0);
      acc[0][3] = __builtin_amdgcn_mfma_f32_16x16x32_bf16(af0, b3, acc[0][3], 0, 0, 0);
      acc[1][3] = __builtin_amdgcn_mfma_f32_16x16x32_bf16(af1, b3, acc[1][3], 0, 0, 0);
      acc[2][3] = __builtin_amdgcn_mfma_f32_16x16x32_bf16(af2, b3, acc[2][3], 0, 0, 0);
      acc[3][3] = __builtin_amdgcn_mfma_f32_16x16x32_bf16(af3, b3, acc[3][3], 0, 0, 0);
    }
  }

  // exp + reduce over g. C/D: col=lm, row=lq*4+reg within each 16x16 tile.
#pragma unroll
  for (int r = 0; r < 4; ++r) {
#pragma unroll
    for (int reg = 0; reg < 4; ++reg) {
      float v = __expf(acc[r][0][reg]) + __expf(acc[r][1][reg]) +
                __expf(acc[r][2][reg]) + __expf(acc[r][3][reg]);
      v += __shfl_down(v, 8, 16);
      v += __shfl_down(v, 4, 16);
      v += __shfl_down(v, 2, 16);
      v += __shfl_down(v, 1, 16);
      if (lm == 0) red[w][r * 16 + lq * 4 + reg] = v;
    }
  }
  __syncthreads();
  if (t < 64) {
    float s = 0.f;
#pragma unroll
    for (int ww = 0; ww < 8; ++ww) s += red[ww][t];
    atomicAdd(&smat[i * 64 + t], s);
  }
}

// ---- final: atts + riv chunk + intent partials (atomic). grid 128, 256 thr
__global__ __launch_bounds__(256) void k_fin(const float* __restrict__ smat,
                                             const float* __restrict__ r_slot,
                                             const float* __restrict__ c_inte,
                                             const float* __restrict__ h,
                                             const float* __restrict__ wia_t,
                                             float* __restrict__ out) {
  __shared__ float av[64], riv[64], red[256];
  const int b = blockIdx.x >> 3, kc = blockIdx.x & 7;
  const int t = threadIdx.x;
  const int w = t >> 6, lane = t & 63;
  for (int r = w * 16; r < w * 16 + 16; ++r) {
    float v = smat[r * 64 + lane];
    float s = v;
    s += __shfl_xor(s, 1);
    s += __shfl_xor(s, 2);
    s += __shfl_xor(s, 4);
    s += __shfl_xor(s, 8);
    s += __shfl_xor(s, 16);
    s += __shfl_xor(s, 32);
    float d = __shfl(v, r);
    if (lane == 0) av[r] = d / s;
  }
  __syncthreads();
  {
    const int hh = kc * 64 + lane;
    float a = 0.f;
    const float* rp = r_slot + (b * 64 + w * 16) * 512 + hh;
#pragma unroll
    for (int i = 0; i < 16; ++i) a += av[w * 16 + i] * rp[i * 512];
    red[t] = a;
  }
  __syncthreads();
  if (t < 64)
    riv[t] = red[t] + red[t + 64] + red[t + 128] + red[t + 192] +
             c_inte[b * 512 + kc * 64 + t];
  __syncthreads();
  {
    const int n = lane;
    const float* hrow = h + (b * 64 + 63) * 512 + kc * 64;
    float p = 0.f;
#pragma unroll
    for (int k = w * 16; k < w * 16 + 16; ++k) {
      p += riv[k] * wia_t[(kc * 64 + k) * 64 + n];
      p += hrow[k] * wia_t[(512 + kc * 64 + k) * 64 + n];
    }
    red[t] = p;
  }
  __syncthreads();
  if (t < 64)
    atomicAdd(&out[b * 64 + t], red[t] + red[t + 64] + red[t + 128] + red[t + 192]);
}

// slot[(b,l),n] = [h[b,l], r_slot[b,l]] @ W_sa[n,:]  via wsa_t
__global__ __launch_bounds__(256) void k_slot(const float* __restrict__ h,
                                              const float* __restrict__ r_slot,
                                              const float* __restrict__ wsa_t,
                                              float* __restrict__ out) {
  int idx = blockIdx.x * 256 + threadIdx.x;  // 65536
  int ml = idx >> 6, n = idx & 63;
  const float* x1 = h + ml * 512;
  const float* x2 = r_slot + ml * 512;
  float acc = 0.f;
  for (int k = 0; k < 512; k += 4) {
    float4 x = *(const float4*)(x1 + k);
    acc += x.x * wsa_t[k * 64 + n] + x.y * wsa_t[(k + 1) * 64 + n] +
           x.z * wsa_t[(k + 2) * 64 + n] + x.w * wsa_t[(k + 3) * 64 + n];
  }
  for (int k = 0; k < 512; k += 4) {
    float4 x = *(const float4*)(x2 + k);
    acc += x.x * wsa_t[(512 + k) * 64 + n] + x.y * wsa_t[(513 + k) * 64 + n] +
           x.z * wsa_t[(514 + k) * 64 + n] + x.w * wsa_t[(515 + k) * 64 + n];
  }
  out[idx] = acc;
}

extern "C" void kernel_launch(void* const* d_in, const int* in_sizes, int n_in,
                              void* d_out, int out_size, void* d_ws, size_t ws_size,
                              hipStream_t stream) {
  const float* h      = (const float*)d_in[0];
  const float* c_slot = (const float*)d_in[1];
  const float* c_inte = (const float*)d_in[2];
  const float* W_SF   = (const float*)d_in[3];
  const float* V_SF   = (const float*)d_in[4];
  const float* V1_ID  = (const float*)d_in[5];
  const float* V2_w   = (const float*)d_in[6];
  const float* V2_b   = (const float*)d_in[7];
  const float* W_ID   = (const float*)d_in[8];
  const float* W_ia   = (const float*)d_in[9];
  const float* W_sa   = (const float*)d_in[10];
  float* out = (float*)d_out;

  float* ws     = (float*)d_ws;
  short* wbp    = (short*)ws;
  short* v2h    = (short*)(ws + 131072);
  short* v2l    = (short*)(ws + 262144);
  short* v1h    = (short*)(ws + 393216);
  short* v1l    = (short*)(ws + 524288);
  float* sfbuf  = ws + 655360;
  float* r_slot = ws + 1179648;
  float* hid    = ws + 1703936;
  float* smat   = ws + 2228224;
  float* f      = ws + 2232320;
  float* wia_t  = ws + 2240512;
  float* wsa_t  = ws + 2306048;

  k_prep<<<1056, 256, 0, stream>>>(W_ID, V2_w, V1_ID, W_ia, W_sa,
                                   wbp, v2h, v2l, v1h, v1l, wia_t, wsa_t);
  k_lin<<<dim3(64, 2), 256, 0, stream>>>(h, nullptr, nullptr, v2h, v2l, V2_b,
                                         sfbuf, r_slot, nullptr, f);

  for (int it = 0; it < 3; ++it) {
    k_mid<<<64, 512, 0, stream>>>(it == 0 ? 1 : 0, smat, r_slot, c_inte,
                                  c_slot, W_SF, V_SF, f);
    k_lin<<<dim3(64, 2), 256, 0, stream>>>(nullptr, c_slot, f, v1h, v1l,
                                           nullptr, hid, r_slot, smat, nullptr);
    k_score<<<dim3(64, 16), 512, 0, stream>>>(hid, sfbuf, wbp, smat, f,
                                              it == 2 ? out : nullptr);
  }

  k_fin<<<128, 256, 0, stream>>>(smat, r_slot, c_inte, h, wia_t, out);
  k_slot<<<256, 256, 0, stream>>>(h, r_slot, wsa_t, out + 1024);
}

// Round 11
// 337.881 us; speedup vs baseline: 3.4233x; 1.0962x over previous
//
#include <hip/hip_runtime.h>
#include <math.h>

// B=16, L=64, H=512, N_LABELS=64, ITERS=3
//
// ws layout (float offsets):
//   wbp 0 [131072] W_ID bf16 B-fragment-major
//   v2h 131072, v2l 262144, v1h 393216, v1l 524288 [131072 each]
//   sfbuf 655360, r_slot 1179648, hid 1703936 [524288 each]
//   smat 2228224 [4096], f 2232320 [8192]
//   wia_t 2240512, wsa_t 2306048 [65536 each]

typedef __attribute__((ext_vector_type(8))) short bf16x8;
typedef __attribute__((ext_vector_type(4))) float f32x4;

__device__ inline short f2bf(float x) {  // RNE
  unsigned u = __float_as_uint(x);
  unsigned r = (u + 0x7fffu + ((u >> 16) & 1u)) >> 16;
  return (short)r;
}
__device__ inline float bf2f(short s) {
  return __uint_as_float(((unsigned)(unsigned short)s) << 16);
}
__device__ inline unsigned pack2(float a, float b) {  // truncating 2xbf16
  return (__float_as_uint(a) >> 16) | (__float_as_uint(b) & 0xffff0000u);
}
__device__ inline float ftanh(float x) {
  float t = __expf(2.f * x);
  return 1.f - 2.f * __builtin_amdgcn_rcpf(t + 1.f);
}

// ---- prep: packs + wia/wsa transposes ----
__global__ __launch_bounds__(256) void k_prep(
    const float* __restrict__ W_ID, const float* __restrict__ V2,
    const float* __restrict__ V1, const float* __restrict__ W_ia,
    const float* __restrict__ W_sa, short* __restrict__ wbp,
    short* __restrict__ v2h, short* __restrict__ v2l,
    short* __restrict__ v1h, short* __restrict__ v1l,
    float* __restrict__ wia_t, float* __restrict__ wsa_t) {
  const int bx = blockIdx.x;
  const int t = threadIdx.x;
  if (bx < 1024) {
    int idx = bx * 256 + t;  // 262144
    int j = idx & 7, lane = (idx >> 3) & 63;
    int ntile = (idx >> 9) & 31, kstep = idx >> 14;
    int g = ntile * 16 + (lane & 15);
    int h = kstep * 32 + (lane >> 4) * 8 + j;
    int src = g * 512 + h;
    wbp[idx] = f2bf(W_ID[src]);
    float x2 = V2[src];
    short h2 = f2bf(x2);
    v2h[idx] = h2;
    v2l[idx] = f2bf(x2 - bf2f(h2));
    float x1 = V1[src];
    short h1 = f2bf(x1);
    v1h[idx] = h1;
    v1l[idx] = f2bf(x1 - bf2f(h1));
  } else {
    const float* tin;
    float* tout;
    int c0;
    if (bx < 1040) { tin = W_ia; tout = wia_t; c0 = (bx - 1024) * 64; }
    else           { tin = W_sa; tout = wsa_t; c0 = (bx - 1040) * 64; }
    __shared__ float tile[64][65];
    const int tx = t & 63, ty = t >> 6;
#pragma unroll
    for (int it2 = 0; it2 < 16; ++it2) {
      int rl = ty + it2 * 4;
      tile[rl][tx] = tin[rl * 1024 + c0 + tx];
    }
    __syncthreads();
#pragma unroll
    for (int it2 = 0; it2 < 16; ++it2) {
      int cl = ty + it2 * 4;
      tout[(c0 + cl) * 64 + tx] = tile[tx][cl];
    }
  }
}

// ---- split-precision MFMA linear: C[M,512] = A[M,512] @ W[512,512]^T (+bias)
// grid (64, 4): 256 blocks. Wave w owns ntiles nh*8 + w*2 + {0,1}.
// mode0 (f==null): A read directly.  mode1 (f!=null): A = f[b,:] (x) c_slot,
// and nh==0 blocks write r_slot rows as a side effect.
__global__ __launch_bounds__(256) void k_lin(const float* __restrict__ A,
                                             const float* __restrict__ c_slot,
                                             const float* __restrict__ f,
                                             const short* __restrict__ bh,
                                             const short* __restrict__ bl,
                                             const float* __restrict__ bias,
                                             float* __restrict__ C,
                                             float* __restrict__ rs_out,
                                             float* __restrict__ smat0,
                                             float* __restrict__ fzero) {
  __shared__ short Ah[2][512], Al[2][512];
  __shared__ float fl[512];
  const int m0 = blockIdx.x * 16;
  const int nh = blockIdx.y;
  const int t = threadIdx.x;
  if (smat0 && nh == 0 && blockIdx.x < 8) {
    smat0[blockIdx.x * 512 + t] = 0.f;
    smat0[blockIdx.x * 512 + 256 + t] = 0.f;
  }
  if (fzero && nh == 1 && blockIdx.x < 16) {
    fzero[blockIdx.x * 512 + t] = 0.f;
    fzero[blockIdx.x * 512 + 256 + t] = 0.f;
  }
  if (f) {
    fl[t] = f[(blockIdx.x >> 2) * 512 + t];
    fl[t + 256] = f[(blockIdx.x >> 2) * 512 + 256 + t];
  }
  const int w = t >> 6, lane = t & 63;
  const int lq = lane >> 4, lm = lane & 15;
  f32x4 acc[2];
#pragma unroll
  for (int c = 0; c < 2; ++c) acc[c] = (f32x4){0.f, 0.f, 0.f, 0.f};

  const bf16x8* gbh = (const bf16x8*)bh + (nh * 8 + w * 2) * 64 + lane;
  const bf16x8* gbl = (const bf16x8*)bl + (nh * 8 + w * 2) * 64 + lane;

  const int la = t >> 2, j0 = (t & 3) * 2;
  const int m = la & 15, kk = (la >> 4) * 8 + j0;
  const float* abase = (f ? c_slot : A) + (m0 + m) * 512 + kk;
  float* rbase = rs_out + (m0 + m) * 512 + kk;
  if (f) __syncthreads();
  float2 x = *(const float2*)abase;

  for (int ks = 0; ks < 16; ++ks) {
    const int buf = ks & 1;
    bf16x8 b0h = gbh[ks * 2048];
    bf16x8 b1h = gbh[ks * 2048 + 64];
    bf16x8 b0l = gbl[ks * 2048];
    bf16x8 b1l = gbl[ks * 2048 + 64];
    float2 xn = x;
    if (ks < 15) xn = *(const float2*)(abase + (ks + 1) * 32);
    float a0 = x.x, a1 = x.y;
    if (f) {
      a0 *= fl[ks * 32 + kk];
      a1 *= fl[ks * 32 + kk + 1];
      if (nh == 0) *(float2*)(rbase + ks * 32) = make_float2(a0, a1);
    }
    short h0 = f2bf(a0), h1 = f2bf(a1);
    short l0 = f2bf(a0 - bf2f(h0)), l1 = f2bf(a1 - bf2f(h1));
    *(short2*)&Ah[buf][t * 2] = make_short2(h0, h1);
    *(short2*)&Al[buf][t * 2] = make_short2(l0, l1);
    __syncthreads();
    bf16x8 ah = *(const bf16x8*)&Ah[buf][lane * 8];
    bf16x8 al = *(const bf16x8*)&Al[buf][lane * 8];
    acc[0] = __builtin_amdgcn_mfma_f32_16x16x32_bf16(ah, b0h, acc[0], 0, 0, 0);
    acc[0] = __builtin_amdgcn_mfma_f32_16x16x32_bf16(al, b0h, acc[0], 0, 0, 0);
    acc[0] = __builtin_amdgcn_mfma_f32_16x16x32_bf16(ah, b0l, acc[0], 0, 0, 0);
    acc[1] = __builtin_amdgcn_mfma_f32_16x16x32_bf16(ah, b1h, acc[1], 0, 0, 0);
    acc[1] = __builtin_amdgcn_mfma_f32_16x16x32_bf16(al, b1h, acc[1], 0, 0, 0);
    acc[1] = __builtin_amdgcn_mfma_f32_16x16x32_bf16(ah, b1l, acc[1], 0, 0, 0);
    x = xn;
  }
#pragma unroll
  for (int c = 0; c < 2; ++c)
#pragma unroll
    for (int reg = 0; reg < 4; ++reg) {
      int mm = m0 + lq * 4 + reg;
      int n = nh * 128 + (w * 2 + c) * 16 + lm;
      float v = acc[c][reg];
      if (bias) v += bias[n];
      C[mm * 512 + n] = v;
    }
}

// ---- per-iteration mid chain (unchanged) ----
__global__ __launch_bounds__(512) void k_mid(int first,
                                             const float* __restrict__ smat,
                                             const float* __restrict__ r_slot,
                                             const float* __restrict__ c_inte,
                                             const float* __restrict__ c_slot,
                                             const float* __restrict__ W_SF,
                                             const float* __restrict__ V_SF,
                                             float* __restrict__ f) {
  __shared__ float av[64];
  __shared__ float rl[512];
  __shared__ float red[512];
  __shared__ float tm[128];
  __shared__ float ts[128];
  const int b = blockIdx.x >> 2, q = blockIdx.x & 3;
  const int t = threadIdx.x;

  if (first) {
    rl[t] = c_inte[b * 512 + t];
    __syncthreads();
  } else {
    if (t < 256) {
      int w = t >> 6, lane = t & 63;
      for (int r = w * 16; r < w * 16 + 16; ++r) {
        float v = smat[r * 64 + lane];
        float s = v;
        s += __shfl_xor(s, 1);
        s += __shfl_xor(s, 2);
        s += __shfl_xor(s, 4);
        s += __shfl_xor(s, 8);
        s += __shfl_xor(s, 16);
        s += __shfl_xor(s, 32);
        float d = __shfl(v, r);
        if (lane == 0) av[r] = d / s;
      }
    }
    __syncthreads();
    float a = 0.f;
    const float* rp = r_slot + b * 64 * 512 + t;
#pragma unroll 8
    for (int i = 0; i < 64; ++i) a += av[i] * rp[i * 512];
    rl[t] = a + c_inte[b * 512 + t];
    __syncthreads();
  }

  {
    const int hh = q * 128 + (t >> 2), kq = t & 3;
    const float* wr = W_SF + hh * 512 + kq * 128;
    const float* rv = rl + kq * 128;
    float p = 0.f;
    for (int k = 0; k < 128; k += 4) {
      float4 wv = *(const float4*)(wr + k);
      p += rv[k] * wv.x + rv[k + 1] * wv.y + rv[k + 2] * wv.z + rv[k + 3] * wv.w;
    }
    red[t] = p;
  }
  __syncthreads();
  if (t < 128) tm[t] = red[t * 4] + red[t * 4 + 1] + red[t * 4 + 2] + red[t * 4 + 3];
  __syncthreads();
  {
    const int hh = q * 128 + (t >> 2), lc = t & 3;
    float tmp_h = tm[t >> 2];
    const float* cp = c_slot + (b * 64 + lc * 16) * 512 + hh;
    float s = 0.f;
    for (int l = 0; l < 16; ++l) s += ftanh(cp[l * 512] + tmp_h);
    red[t] = s;
  }
  __syncthreads();
  if (t < 128) ts[t] = red[t * 4] + red[t * 4 + 1] + red[t * 4 + 2] + red[t * 4 + 3];
  __syncthreads();
  {
    const float* vr = V_SF + t * 512 + q * 128;
    float p = 0.f;
    for (int k = 0; k < 128; k += 4) {
      float4 vv = *(const float4*)(vr + k);
      p += ts[k] * vv.x + ts[k + 1] * vv.y + ts[k + 2] * vv.z + ts[k + 3] * vv.w;
    }
    atomicAdd(&f[b * 512 + t], p);
  }
}

// ---- dominant kernel v7: whole A tile (64j x 512k bf16 = 64KB) staged once,
// ONE barrier, then a barrier-free MFMA loop with B prefetched one kstep ahead.
// grid (64 i, 16 b); 512 thr = 8 waves; wave w owns ntiles w*4..w*4+3.
__global__ __launch_bounds__(512, 4) void k_score(const float* __restrict__ hid,
                                                  const float* __restrict__ sf,
                                                  const short* __restrict__ wbp,
                                                  float* __restrict__ smat,
                                                  float* __restrict__ fz,
                                                  float* __restrict__ oz) {
  __shared__ short As[16][2048];  // 64 KB, [ks][mtile*64+lane][8]
  __shared__ float red[8][64];
  const int i = blockIdx.x, b = blockIdx.y;
  const int t = threadIdx.x;
  if (fz && i == 0) fz[b * 512 + t] = 0.f;
  if (oz && i == 1 && b < 2) oz[b * 512 + t] = 0.f;
  const int w = t >> 6, lane = t & 63;
  const int lq = lane >> 4, lm = lane & 15;

  f32x4 acc[4][4];
#pragma unroll
  for (int r = 0; r < 4; ++r)
#pragma unroll
    for (int c = 0; c < 4; ++c) acc[r][c] = (f32x4){0.f, 0.f, 0.f, 0.f};

  const float* hrow = hid + (b * 64 + i) * 512;
  const float* sfb = sf + b * 64 * 512;

  const int fid = t >> 1, half = t & 1;
  const int am = (fid >> 6) * 16 + (fid & 15);      // j row staged
  const int ak = ((fid >> 4) & 3) * 8 + half * 4;   // k offset in 32-k slab
  const int aoff = fid * 8 + half * 4;

  const float* hp0 = hrow + ak;
  const float* sp0 = sfb + am * 512 + ak;

  // ---- stage entire A: 16 slabs of tanh -> bf16, fragment order ----
#pragma unroll 4
  for (int ks = 0; ks < 16; ++ks) {
    float4 hv = *(const float4*)(hp0 + ks * 32);
    float4 sv = *(const float4*)(sp0 + ks * 32);
    uint2 pk;
    pk.x = pack2(ftanh(hv.x + sv.x), ftanh(hv.y + sv.y));
    pk.y = pack2(ftanh(hv.z + sv.z), ftanh(hv.w + sv.w));
    *(uint2*)&As[ks][aoff] = pk;
  }
  __syncthreads();

  // ---- barrier-free MFMA loop, B prefetched one kstep ahead ----
  const bf16x8* gb = (const bf16x8*)wbp + (w * 4) * 64 + lane;
  bf16x8 nb0 = gb[0];
  bf16x8 nb1 = gb[64];
  bf16x8 nb2 = gb[128];
  bf16x8 nb3 = gb[192];
  for (int ks = 0; ks < 16; ++ks) {
    bf16x8 b0 = nb0, b1 = nb1, b2 = nb2, b3 = nb3;
    if (ks < 15) {
      nb0 = gb[(ks + 1) * 2048];
      nb1 = gb[(ks + 1) * 2048 + 64];
      nb2 = gb[(ks + 1) * 2048 + 128];
      nb3 = gb[(ks + 1) * 2048 + 192];
    }
    bf16x8 af0 = *(const bf16x8*)&As[ks][(0 * 64 + lane) * 8];
    bf16x8 af1 = *(const bf16x8*)&As[ks][(1 * 64 + lane) * 8];
    bf16x8 af2 = *(const bf16x8*)&As[ks][(2 * 64 + lane) * 8];
    bf16x8 af3 = *(const bf16x8*)&As[ks][(3 * 64 + lane) * 8];
    acc[0][0] = __builtin_amdgcn_mfma_f32_16x16x32_bf16(af0, b0, acc[0][0], 0, 0, 0);
    acc[1][0] = __builtin_amdgcn_mfma_f32_16x16x32_bf16(af1, b0, acc[1][0], 0, 0, 0);
    acc[2][0] = __builtin_amdgcn_mfma_f32_16x16x32_bf16(af2, b0, acc[2][0], 0, 0, 0);
    acc[3][0] = __builtin_amdgcn_mfma_f32_16x16x32_bf16(af3, b0, acc[3][0], 0, 0, 0);
    acc[0][1] = __builtin_amdgcn_mfma_f32_16x16x32_bf16(af0, b1, acc[0][1], 0, 0, 0);
    acc[1][1] = __builtin_amdgcn_mfma_f32_16x16x32_bf16(af1, b1, acc[1][1], 0, 0, 0);
    acc[2][1] = __builtin_amdgcn_mfma_f32_16x16x32_bf16(af2, b1, acc[2][1], 0, 0, 0);
    acc[3][1] = __builtin_amdgcn_mfma_f32_16x16x32_bf16(af3, b1, acc[3][1], 0, 0, 0);
    acc[0][2] = __builtin_amdgcn_mfma_f32_16x16x32_bf16(af0, b2, acc[0][2], 0, 0, 0);
    acc[1][2] = __builtin_amdgcn_mfma_f32_16x16x32_bf16(af1, b2, acc[1][2], 0, 0, 0);
    acc[2][2] = __builtin_amdgcn_mfma_f32_16x16x32_bf16(af2, b2, acc[2][2], 0, 0, 0);
    acc[3][2] = __builtin_amdgcn_mfma_f32_16x16x32_bf16(af3, b2, acc[3][2], 0, 0, 0);
    acc[0][3] = __builtin_amdgcn_mfma_f32_16x16x32_bf16(af0, b3, acc[0][3], 0, 0, 0);
    acc[1][3] = __builtin_amdgcn_mfma_f32_16x16x32_bf16(af1, b3, acc[1][3], 0, 0, 0);
    acc[2][3] = __builtin_amdgcn_mfma_f32_16x16x32_bf16(af2, b3, acc[2][3], 0, 0, 0);
    acc[3][3] = __builtin_amdgcn_mfma_f32_16x16x32_bf16(af3, b3, acc[3][3], 0, 0, 0);
  }

  // exp + reduce over g. C/D: col=lm, row=lq*4+reg within each 16x16 tile.
#pragma unroll
  for (int r = 0; r < 4; ++r) {
#pragma unroll
    for (int reg = 0; reg < 4; ++reg) {
      float v = __expf(acc[r][0][reg]) + __expf(acc[r][1][reg]) +
                __expf(acc[r][2][reg]) + __expf(acc[r][3][reg]);
      v += __shfl_down(v, 8, 16);
      v += __shfl_down(v, 4, 16);
      v += __shfl_down(v, 2, 16);
      v += __shfl_down(v, 1, 16);
      if (lm == 0) red[w][r * 16 + lq * 4 + reg] = v;
    }
  }
  __syncthreads();
  if (t < 64) {
    float s = 0.f;
#pragma unroll
    for (int ww = 0; ww < 8; ++ww) s += red[ww][t];
    atomicAdd(&smat[i * 64 + t], s);
  }
}

// ---- post: k_slot (bx<256) + k_fin (bx>=256) merged ----
__global__ __launch_bounds__(256) void k_post(const float* __restrict__ smat,
                                              const float* __restrict__ r_slot,
                                              const float* __restrict__ c_inte,
                                              const float* __restrict__ h,
                                              const float* __restrict__ wia_t,
                                              const float* __restrict__ wsa_t,
                                              float* __restrict__ out) {
  __shared__ float av[64], riv[64], red[256];
  const int t = threadIdx.x;
  if (blockIdx.x < 256) {
    // slot[(b,l),n] = [h[b,l], r_slot[b,l]] @ W_sa[n,:]
    int idx = blockIdx.x * 256 + t;  // 65536
    int ml = idx >> 6, n = idx & 63;
    const float* x1 = h + ml * 512;
    const float* x2 = r_slot + ml * 512;
    float acc = 0.f;
    for (int k = 0; k < 512; k += 4) {
      float4 x = *(const float4*)(x1 + k);
      acc += x.x * wsa_t[k * 64 + n] + x.y * wsa_t[(k + 1) * 64 + n] +
             x.z * wsa_t[(k + 2) * 64 + n] + x.w * wsa_t[(k + 3) * 64 + n];
    }
    for (int k = 0; k < 512; k += 4) {
      float4 x = *(const float4*)(x2 + k);
      acc += x.x * wsa_t[(512 + k) * 64 + n] + x.y * wsa_t[(513 + k) * 64 + n] +
             x.z * wsa_t[(514 + k) * 64 + n] + x.w * wsa_t[(515 + k) * 64 + n];
    }
    out[1024 + idx] = acc;
  } else {
    // fin: atts + riv chunk + intent partials (atomic)
    const int bb = blockIdx.x - 256;
    const int b = bb >> 3, kc = bb & 7;
    const int w = t >> 6, lane = t & 63;
    for (int r = w * 16; r < w * 16 + 16; ++r) {
      float v = smat[r * 64 + lane];
      float s = v;
      s += __shfl_xor(s, 1);
      s += __shfl_xor(s, 2);
      s += __shfl_xor(s, 4);
      s += __shfl_xor(s, 8);
      s += __shfl_xor(s, 16);
      s += __shfl_xor(s, 32);
      float d = __shfl(v, r);
      if (lane == 0) av[r] = d / s;
    }
    __syncthreads();
    {
      const int hh = kc * 64 + lane;
      float a = 0.f;
      const float* rp = r_slot + (b * 64 + w * 16) * 512 + hh;
#pragma unroll
      for (int i = 0; i < 16; ++i) a += av[w * 16 + i] * rp[i * 512];
      red[t] = a;
    }
    __syncthreads();
    if (t < 64)
      riv[t] = red[t] + red[t + 64] + red[t + 128] + red[t + 192] +
               c_inte[b * 512 + kc * 64 + t];
    __syncthreads();
    {
      const int n = lane;
      const float* hrow = h + (b * 64 + 63) * 512 + kc * 64;
      float p = 0.f;
#pragma unroll
      for (int k = w * 16; k < w * 16 + 16; ++k) {
        p += riv[k] * wia_t[(kc * 64 + k) * 64 + n];
        p += hrow[k] * wia_t[(512 + kc * 64 + k) * 64 + n];
      }
      red[t] = p;
    }
    __syncthreads();
    if (t < 64)
      atomicAdd(&out[b * 64 + t],
                red[t] + red[t + 64] + red[t + 128] + red[t + 192]);
  }
}

extern "C" void kernel_launch(void* const* d_in, const int* in_sizes, int n_in,
                              void* d_out, int out_size, void* d_ws, size_t ws_size,
                              hipStream_t stream) {
  const float* h      = (const float*)d_in[0];
  const float* c_slot = (const float*)d_in[1];
  const float* c_inte = (const float*)d_in[2];
  const float* W_SF   = (const float*)d_in[3];
  const float* V_SF   = (const float*)d_in[4];
  const float* V1_ID  = (const float*)d_in[5];
  const float* V2_w   = (const float*)d_in[6];
  const float* V2_b   = (const float*)d_in[7];
  const float* W_ID   = (const float*)d_in[8];
  const float* W_ia   = (const float*)d_in[9];
  const float* W_sa   = (const float*)d_in[10];
  float* out = (float*)d_out;

  float* ws     = (float*)d_ws;
  short* wbp    = (short*)ws;
  short* v2h    = (short*)(ws + 131072);
  short* v2l    = (short*)(ws + 262144);
  short* v1h    = (short*)(ws + 393216);
  short* v1l    = (short*)(ws + 524288);
  float* sfbuf  = ws + 655360;
  float* r_slot = ws + 1179648;
  float* hid    = ws + 1703936;
  float* smat   = ws + 2228224;
  float* f      = ws + 2232320;
  float* wia_t  = ws + 2240512;
  float* wsa_t  = ws + 2306048;

  k_prep<<<1056, 256, 0, stream>>>(W_ID, V2_w, V1_ID, W_ia, W_sa,
                                   wbp, v2h, v2l, v1h, v1l, wia_t, wsa_t);
  k_lin<<<dim3(64, 4), 256, 0, stream>>>(h, nullptr, nullptr, v2h, v2l, V2_b,
                                         sfbuf, r_slot, nullptr, f);

  for (int it = 0; it < 3; ++it) {
    k_mid<<<64, 512, 0, stream>>>(it == 0 ? 1 : 0, smat, r_slot, c_inte,
                                  c_slot, W_SF, V_SF, f);
    k_lin<<<dim3(64, 4), 256, 0, stream>>>(nullptr, c_slot, f, v1h, v1l,
                                           nullptr, hid, r_slot, smat, nullptr);
    k_score<<<dim3(64, 16), 512, 0, stream>>>(hid, sfbuf, wbp, smat, f,
                                              it == 2 ? out : nullptr);
  }

  k_post<<<384, 256, 0, stream>>>(smat, r_slot, c_inte, h, wia_t, wsa_t, out);
}

// Round 12
// 306.268 us; speedup vs baseline: 3.7766x; 1.1032x over previous
//
#include <hip/hip_runtime.h>
#include <math.h>

// B=16, L=64, H=512, N_LABELS=64, ITERS=3
//
// ws layout (float offsets):
//   wbp 0 [131072] W_ID bf16 B-fragment-major
//   v2h 131072, v2l 262144, v1h 393216, v1l 524288 [131072 each]
//   sfbuf 655360, r_slot 1179648, hid 1703936 [524288 each]
//   smat 2228224 [4096], f 2232320 [8192]
//   wia_t 2240512, wsa_t 2306048 [65536 each]
//   wsf_t 2371584, vsf_t 2633728 [262144 each]  (end ~2.9M f = 11.6 MB)

typedef __attribute__((ext_vector_type(8))) short bf16x8;
typedef __attribute__((ext_vector_type(4))) float f32x4;

__device__ inline short f2bf(float x) {  // RNE
  unsigned u = __float_as_uint(x);
  unsigned r = (u + 0x7fffu + ((u >> 16) & 1u)) >> 16;
  return (short)r;
}
__device__ inline float bf2f(short s) {
  return __uint_as_float(((unsigned)(unsigned short)s) << 16);
}
__device__ inline unsigned pack2(float a, float b) {  // truncating 2xbf16
  return (__float_as_uint(a) >> 16) | (__float_as_uint(b) & 0xffff0000u);
}
__device__ inline float ftanh(float x) {
  float t = __expf(2.f * x);
  return 1.f - 2.f * __builtin_amdgcn_rcpf(t + 1.f);
}

// ---- prep: packs + wia/wsa transposes + wsf/vsf transposes ----
__global__ __launch_bounds__(256) void k_prep(
    const float* __restrict__ W_ID, const float* __restrict__ V2,
    const float* __restrict__ V1, const float* __restrict__ W_ia,
    const float* __restrict__ W_sa, const float* __restrict__ W_SF,
    const float* __restrict__ V_SF, short* __restrict__ wbp,
    short* __restrict__ v2h, short* __restrict__ v2l,
    short* __restrict__ v1h, short* __restrict__ v1l,
    float* __restrict__ wia_t, float* __restrict__ wsa_t,
    float* __restrict__ wsf_t, float* __restrict__ vsf_t) {
  const int bx = blockIdx.x;
  const int t = threadIdx.x;
  if (bx < 1024) {
    int idx = bx * 256 + t;  // 262144
    int j = idx & 7, lane = (idx >> 3) & 63;
    int ntile = (idx >> 9) & 31, kstep = idx >> 14;
    int g = ntile * 16 + (lane & 15);
    int h = kstep * 32 + (lane >> 4) * 8 + j;
    int src = g * 512 + h;
    wbp[idx] = f2bf(W_ID[src]);
    float x2 = V2[src];
    short h2 = f2bf(x2);
    v2h[idx] = h2;
    v2l[idx] = f2bf(x2 - bf2f(h2));
    float x1 = V1[src];
    short h1 = f2bf(x1);
    v1h[idx] = h1;
    v1l[idx] = f2bf(x1 - bf2f(h1));
  } else {
    const float* tin;
    float* tout;
    int R, C, c0, r0;
    if (bx < 1040) {
      tin = W_ia; tout = wia_t; R = 64; C = 1024;
      c0 = (bx - 1024) * 64; r0 = 0;
    } else if (bx < 1056) {
      tin = W_sa; tout = wsa_t; R = 64; C = 1024;
      c0 = (bx - 1040) * 64; r0 = 0;
    } else if (bx < 1120) {
      int bxx = bx - 1056;
      tin = W_SF; tout = wsf_t; R = 512; C = 512;
      c0 = (bxx & 7) * 64; r0 = (bxx >> 3) * 64;
    } else {
      int bxx = bx - 1120;
      tin = V_SF; tout = vsf_t; R = 512; C = 512;
      c0 = (bxx & 7) * 64; r0 = (bxx >> 3) * 64;
    }
    __shared__ float tile[64][65];
    const int tx = t & 63, ty = t >> 6;
#pragma unroll
    for (int it2 = 0; it2 < 16; ++it2) {
      int rl = ty + it2 * 4;
      tile[rl][tx] = tin[(r0 + rl) * C + c0 + tx];
    }
    __syncthreads();
#pragma unroll
    for (int it2 = 0; it2 < 16; ++it2) {
      int cl = ty + it2 * 4;
      tout[(c0 + cl) * R + r0 + tx] = tile[tx][cl];
    }
  }
}

// ---- split-precision MFMA linear: C[M,512] = A[M,512] @ W[512,512]^T (+bias)
// grid (64, 4): 256 blocks. Wave w owns ntiles nh*8 + w*2 + {0,1}.
// mode0 (f==null): A read directly.  mode1 (f!=null): A = f[b,:] (x) c_slot,
// and nh==0 blocks write r_slot rows as a side effect.
__global__ __launch_bounds__(256) void k_lin(const float* __restrict__ A,
                                             const float* __restrict__ c_slot,
                                             const float* __restrict__ f,
                                             const short* __restrict__ bh,
                                             const short* __restrict__ bl,
                                             const float* __restrict__ bias,
                                             float* __restrict__ C,
                                             float* __restrict__ rs_out,
                                             float* __restrict__ smat0,
                                             float* __restrict__ fzero) {
  __shared__ short Ah[2][512], Al[2][512];
  __shared__ float fl[512];
  const int m0 = blockIdx.x * 16;
  const int nh = blockIdx.y;
  const int t = threadIdx.x;
  if (smat0 && nh == 0 && blockIdx.x < 8) {
    smat0[blockIdx.x * 512 + t] = 0.f;
    smat0[blockIdx.x * 512 + 256 + t] = 0.f;
  }
  if (fzero && nh == 1 && blockIdx.x < 16) {
    fzero[blockIdx.x * 512 + t] = 0.f;
    fzero[blockIdx.x * 512 + 256 + t] = 0.f;
  }
  if (f) {
    fl[t] = f[(blockIdx.x >> 2) * 512 + t];
    fl[t + 256] = f[(blockIdx.x >> 2) * 512 + 256 + t];
  }
  const int w = t >> 6, lane = t & 63;
  const int lq = lane >> 4, lm = lane & 15;
  f32x4 acc[2];
#pragma unroll
  for (int c = 0; c < 2; ++c) acc[c] = (f32x4){0.f, 0.f, 0.f, 0.f};

  const bf16x8* gbh = (const bf16x8*)bh + (nh * 8 + w * 2) * 64 + lane;
  const bf16x8* gbl = (const bf16x8*)bl + (nh * 8 + w * 2) * 64 + lane;

  const int la = t >> 2, j0 = (t & 3) * 2;
  const int m = la & 15, kk = (la >> 4) * 8 + j0;
  const float* abase = (f ? c_slot : A) + (m0 + m) * 512 + kk;
  float* rbase = rs_out + (m0 + m) * 512 + kk;
  if (f) __syncthreads();
  float2 x = *(const float2*)abase;

  for (int ks = 0; ks < 16; ++ks) {
    const int buf = ks & 1;
    bf16x8 b0h = gbh[ks * 2048];
    bf16x8 b1h = gbh[ks * 2048 + 64];
    bf16x8 b0l = gbl[ks * 2048];
    bf16x8 b1l = gbl[ks * 2048 + 64];
    float2 xn = x;
    if (ks < 15) xn = *(const float2*)(abase + (ks + 1) * 32);
    float a0 = x.x, a1 = x.y;
    if (f) {
      a0 *= fl[ks * 32 + kk];
      a1 *= fl[ks * 32 + kk + 1];
      if (nh == 0) *(float2*)(rbase + ks * 32) = make_float2(a0, a1);
    }
    short h0 = f2bf(a0), h1 = f2bf(a1);
    short l0 = f2bf(a0 - bf2f(h0)), l1 = f2bf(a1 - bf2f(h1));
    *(short2*)&Ah[buf][t * 2] = make_short2(h0, h1);
    *(short2*)&Al[buf][t * 2] = make_short2(l0, l1);
    __syncthreads();
    bf16x8 ah = *(const bf16x8*)&Ah[buf][lane * 8];
    bf16x8 al = *(const bf16x8*)&Al[buf][lane * 8];
    acc[0] = __builtin_amdgcn_mfma_f32_16x16x32_bf16(ah, b0h, acc[0], 0, 0, 0);
    acc[0] = __builtin_amdgcn_mfma_f32_16x16x32_bf16(al, b0h, acc[0], 0, 0, 0);
    acc[0] = __builtin_amdgcn_mfma_f32_16x16x32_bf16(ah, b0l, acc[0], 0, 0, 0);
    acc[1] = __builtin_amdgcn_mfma_f32_16x16x32_bf16(ah, b1h, acc[1], 0, 0, 0);
    acc[1] = __builtin_amdgcn_mfma_f32_16x16x32_bf16(al, b1h, acc[1], 0, 0, 0);
    acc[1] = __builtin_amdgcn_mfma_f32_16x16x32_bf16(ah, b1l, acc[1], 0, 0, 0);
    x = xn;
  }
#pragma unroll
  for (int c = 0; c < 2; ++c)
#pragma unroll
    for (int reg = 0; reg < 4; ++reg) {
      int mm = m0 + lq * 4 + reg;
      int n = nh * 128 + (w * 2 + c) * 16 + lm;
      float v = acc[c][reg];
      if (bias) v += bias[n];
      C[mm * 512 + n] = v;
    }
}

// ---- per-iteration mid chain v2: fully coalesced via wsf_t/vsf_t.
// grid 128 = (b 16 x hc 8); 512 thr. atts+riv recomputed per block (coalesced).
__global__ __launch_bounds__(512) void k_mid(int first,
                                             const float* __restrict__ smat,
                                             const float* __restrict__ r_slot,
                                             const float* __restrict__ c_inte,
                                             const float* __restrict__ c_slot,
                                             const float* __restrict__ wsf_t,
                                             const float* __restrict__ vsf_t,
                                             float* __restrict__ f) {
  __shared__ float av[64];
  __shared__ float riv[512];
  __shared__ float red[512];
  __shared__ float tm[64], ts[64];
  const int b = blockIdx.x >> 3, hc = blockIdx.x & 7;
  const int t = threadIdx.x;
  const int hl = t & 63, kq = t >> 6;

  if (first) {
    riv[t] = c_inte[b * 512 + t];
  } else {
    if (t < 256) {
      int w = t >> 6, lane = t & 63;
      for (int r = w * 16; r < w * 16 + 16; ++r) {
        float v = smat[r * 64 + lane];
        float s = v;
        s += __shfl_xor(s, 1);
        s += __shfl_xor(s, 2);
        s += __shfl_xor(s, 4);
        s += __shfl_xor(s, 8);
        s += __shfl_xor(s, 16);
        s += __shfl_xor(s, 32);
        float d = __shfl(v, r);
        if (lane == 0) av[r] = d / s;
      }
    }
    __syncthreads();
    float a = 0.f;
    const float* rp = r_slot + b * 64 * 512 + t;
#pragma unroll 8
    for (int i = 0; i < 64; ++i) a += av[i] * rp[i * 512];
    riv[t] = a + c_inte[b * 512 + t];
  }
  __syncthreads();
  // tmp chunk: h = hc*64 + hl; k-split 8 ways (kq)
  {
    const float* wp = wsf_t + hc * 64 + hl;  // + k*512
    float p = 0.f;
#pragma unroll 8
    for (int k = kq * 64; k < kq * 64 + 64; ++k) p += riv[k] * wp[k * 512];
    red[t] = p;
  }
  __syncthreads();
  if (t < 64) {
    float s = 0.f;
#pragma unroll
    for (int q = 0; q < 8; ++q) s += red[q * 64 + t];
    tm[t] = s;
  }
  __syncthreads();
  // tanh-sum chunk: l-split 8 ways (kq, 8 l each)
  {
    float tmph = tm[hl];
    const float* cp = c_slot + (b * 64 + kq * 8) * 512 + hc * 64 + hl;
    float s = 0.f;
#pragma unroll
    for (int l = 0; l < 8; ++l) s += ftanh(cp[l * 512] + tmph);
    red[t] = s;
  }
  __syncthreads();
  if (t < 64) {
    float s = 0.f;
#pragma unroll
    for (int q = 0; q < 8; ++q) s += red[q * 64 + t];
    ts[t] = s;
  }
  __syncthreads();
  // f partials: n = t, k over this block's 64-h chunk
  {
    const float* vp = vsf_t + (hc * 64) * 512 + t;
    float p = 0.f;
#pragma unroll 8
    for (int k = 0; k < 64; ++k) p += ts[k] * vp[k * 512];
    atomicAdd(&f[b * 512 + t], p);
  }
}

// ---- dominant kernel v7 (unchanged): whole A staged once, 1 barrier ----
__global__ __launch_bounds__(512, 4) void k_score(const float* __restrict__ hid,
                                                  const float* __restrict__ sf,
                                                  const short* __restrict__ wbp,
                                                  float* __restrict__ smat,
                                                  float* __restrict__ fz,
                                                  float* __restrict__ oz) {
  __shared__ short As[16][2048];  // 64 KB
  __shared__ float red[8][64];
  const int i = blockIdx.x, b = blockIdx.y;
  const int t = threadIdx.x;
  if (fz && i == 0) fz[b * 512 + t] = 0.f;
  if (oz && i == 1 && b < 2) oz[b * 512 + t] = 0.f;
  const int w = t >> 6, lane = t & 63;
  const int lq = lane >> 4, lm = lane & 15;

  f32x4 acc[4][4];
#pragma unroll
  for (int r = 0; r < 4; ++r)
#pragma unroll
    for (int c = 0; c < 4; ++c) acc[r][c] = (f32x4){0.f, 0.f, 0.f, 0.f};

  const float* hrow = hid + (b * 64 + i) * 512;
  const float* sfb = sf + b * 64 * 512;

  const int fid = t >> 1, half = t & 1;
  const int am = (fid >> 6) * 16 + (fid & 15);
  const int ak = ((fid >> 4) & 3) * 8 + half * 4;
  const int aoff = fid * 8 + half * 4;

  const float* hp0 = hrow + ak;
  const float* sp0 = sfb + am * 512 + ak;

#pragma unroll 4
  for (int ks = 0; ks < 16; ++ks) {
    float4 hv = *(const float4*)(hp0 + ks * 32);
    float4 sv = *(const float4*)(sp0 + ks * 32);
    uint2 pk;
    pk.x = pack2(ftanh(hv.x + sv.x), ftanh(hv.y + sv.y));
    pk.y = pack2(ftanh(hv.z + sv.z), ftanh(hv.w + sv.w));
    *(uint2*)&As[ks][aoff] = pk;
  }
  __syncthreads();

  const bf16x8* gb = (const bf16x8*)wbp + (w * 4) * 64 + lane;
  bf16x8 nb0 = gb[0];
  bf16x8 nb1 = gb[64];
  bf16x8 nb2 = gb[128];
  bf16x8 nb3 = gb[192];
  for (int ks = 0; ks < 16; ++ks) {
    bf16x8 b0 = nb0, b1 = nb1, b2 = nb2, b3 = nb3;
    if (ks < 15) {
      nb0 = gb[(ks + 1) * 2048];
      nb1 = gb[(ks + 1) * 2048 + 64];
      nb2 = gb[(ks + 1) * 2048 + 128];
      nb3 = gb[(ks + 1) * 2048 + 192];
    }
    bf16x8 af0 = *(const bf16x8*)&As[ks][(0 * 64 + lane) * 8];
    bf16x8 af1 = *(const bf16x8*)&As[ks][(1 * 64 + lane) * 8];
    bf16x8 af2 = *(const bf16x8*)&As[ks][(2 * 64 + lane) * 8];
    bf16x8 af3 = *(const bf16x8*)&As[ks][(3 * 64 + lane) * 8];
    acc[0][0] = __builtin_amdgcn_mfma_f32_16x16x32_bf16(af0, b0, acc[0][0], 0, 0, 0);
    acc[1][0] = __builtin_amdgcn_mfma_f32_16x16x32_bf16(af1, b0, acc[1][0], 0, 0, 0);
    acc[2][0] = __builtin_amdgcn_mfma_f32_16x16x32_bf16(af2, b0, acc[2][0], 0, 0, 0);
    acc[3][0] = __builtin_amdgcn_mfma_f32_16x16x32_bf16(af3, b0, acc[3][0], 0, 0, 0);
    acc[0][1] = __builtin_amdgcn_mfma_f32_16x16x32_bf16(af0, b1, acc[0][1], 0, 0, 0);
    acc[1][1] = __builtin_amdgcn_mfma_f32_16x16x32_bf16(af1, b1, acc[1][1], 0, 0, 0);
    acc[2][1] = __builtin_amdgcn_mfma_f32_16x16x32_bf16(af2, b1, acc[2][1], 0, 0, 0);
    acc[3][1] = __builtin_amdgcn_mfma_f32_16x16x32_bf16(af3, b1, acc[3][1], 0, 0, 0);
    acc[0][2] = __builtin_amdgcn_mfma_f32_16x16x32_bf16(af0, b2, acc[0][2], 0, 0, 0);
    acc[1][2] = __builtin_amdgcn_mfma_f32_16x16x32_bf16(af1, b2, acc[1][2], 0, 0, 0);
    acc[2][2] = __builtin_amdgcn_mfma_f32_16x16x32_bf16(af2, b2, acc[2][2], 0, 0, 0);
    acc[3][2] = __builtin_amdgcn_mfma_f32_16x16x32_bf16(af3, b2, acc[3][2], 0, 0, 0);
    acc[0][3] = __builtin_amdgcn_mfma_f32_16x16x32_bf16(af0, b3, acc[0][3], 0, 0, 0);
    acc[1][3] = __builtin_amdgcn_mfma_f32_16x16x32_bf16(af1, b3, acc[1][3], 0, 0, 0);
    acc[2][3] = __builtin_amdgcn_mfma_f32_16x16x32_bf16(af2, b3, acc[2][3], 0, 0, 0);
    acc[3][3] = __builtin_amdgcn_mfma_f32_16x16x32_bf16(af3, b3, acc[3][3], 0, 0, 0);
  }

#pragma unroll
  for (int r = 0; r < 4; ++r) {
#pragma unroll
    for (int reg = 0; reg < 4; ++reg) {
      float v = __expf(acc[r][0][reg]) + __expf(acc[r][1][reg]) +
                __expf(acc[r][2][reg]) + __expf(acc[r][3][reg]);
      v += __shfl_down(v, 8, 16);
      v += __shfl_down(v, 4, 16);
      v += __shfl_down(v, 2, 16);
      v += __shfl_down(v, 1, 16);
      if (lm == 0) red[w][r * 16 + lq * 4 + reg] = v;
    }
  }
  __syncthreads();
  if (t < 64) {
    float s = 0.f;
#pragma unroll
    for (int ww = 0; ww < 8; ++ww) s += red[ww][t];
    atomicAdd(&smat[i * 64 + t], s);
  }
}

// ---- post: k_slot (bx<256) + k_fin (bx>=256) merged ----
__global__ __launch_bounds__(256) void k_post(const float* __restrict__ smat,
                                              const float* __restrict__ r_slot,
                                              const float* __restrict__ c_inte,
                                              const float* __restrict__ h,
                                              const float* __restrict__ wia_t,
                                              const float* __restrict__ wsa_t,
                                              float* __restrict__ out) {
  __shared__ float av[64], riv[64], red[256];
  const int t = threadIdx.x;
  if (blockIdx.x < 256) {
    int idx = blockIdx.x * 256 + t;  // 65536
    int ml = idx >> 6, n = idx & 63;
    const float* x1 = h + ml * 512;
    const float* x2 = r_slot + ml * 512;
    float acc = 0.f;
    for (int k = 0; k < 512; k += 4) {
      float4 x = *(const float4*)(x1 + k);
      acc += x.x * wsa_t[k * 64 + n] + x.y * wsa_t[(k + 1) * 64 + n] +
             x.z * wsa_t[(k + 2) * 64 + n] + x.w * wsa_t[(k + 3) * 64 + n];
    }
    for (int k = 0; k < 512; k += 4) {
      float4 x = *(const float4*)(x2 + k);
      acc += x.x * wsa_t[(512 + k) * 64 + n] + x.y * wsa_t[(513 + k) * 64 + n] +
             x.z * wsa_t[(514 + k) * 64 + n] + x.w * wsa_t[(515 + k) * 64 + n];
    }
    out[1024 + idx] = acc;
  } else {
    const int bb = blockIdx.x - 256;
    const int b = bb >> 3, kc = bb & 7;
    const int w = t >> 6, lane = t & 63;
    for (int r = w * 16; r < w * 16 + 16; ++r) {
      float v = smat[r * 64 + lane];
      float s = v;
      s += __shfl_xor(s, 1);
      s += __shfl_xor(s, 2);
      s += __shfl_xor(s, 4);
      s += __shfl_xor(s, 8);
      s += __shfl_xor(s, 16);
      s += __shfl_xor(s, 32);
      float d = __shfl(v, r);
      if (lane == 0) av[r] = d / s;
    }
    __syncthreads();
    {
      const int hh = kc * 64 + lane;
      float a = 0.f;
      const float* rp = r_slot + (b * 64 + w * 16) * 512 + hh;
#pragma unroll
      for (int i = 0; i < 16; ++i) a += av[w * 16 + i] * rp[i * 512];
      red[t] = a;
    }
    __syncthreads();
    if (t < 64)
      riv[t] = red[t] + red[t + 64] + red[t + 128] + red[t + 192] +
               c_inte[b * 512 + kc * 64 + t];
    __syncthreads();
    {
      const int n = lane;
      const float* hrow = h + (b * 64 + 63) * 512 + kc * 64;
      float p = 0.f;
#pragma unroll
      for (int k = w * 16; k < w * 16 + 16; ++k) {
        p += riv[k] * wia_t[(kc * 64 + k) * 64 + n];
        p += hrow[k] * wia_t[(512 + kc * 64 + k) * 64 + n];
      }
      red[t] = p;
    }
    __syncthreads();
    if (t < 64)
      atomicAdd(&out[b * 64 + t],
                red[t] + red[t + 64] + red[t + 128] + red[t + 192]);
  }
}

extern "C" void kernel_launch(void* const* d_in, const int* in_sizes, int n_in,
                              void* d_out, int out_size, void* d_ws, size_t ws_size,
                              hipStream_t stream) {
  const float* h      = (const float*)d_in[0];
  const float* c_slot = (const float*)d_in[1];
  const float* c_inte = (const float*)d_in[2];
  const float* W_SF   = (const float*)d_in[3];
  const float* V_SF   = (const float*)d_in[4];
  const float* V1_ID  = (const float*)d_in[5];
  const float* V2_w   = (const float*)d_in[6];
  const float* V2_b   = (const float*)d_in[7];
  const float* W_ID   = (const float*)d_in[8];
  const float* W_ia   = (const float*)d_in[9];
  const float* W_sa   = (const float*)d_in[10];
  float* out = (float*)d_out;

  float* ws     = (float*)d_ws;
  short* wbp    = (short*)ws;
  short* v2h    = (short*)(ws + 131072);
  short* v2l    = (short*)(ws + 262144);
  short* v1h    = (short*)(ws + 393216);
  short* v1l    = (short*)(ws + 524288);
  float* sfbuf  = ws + 655360;
  float* r_slot = ws + 1179648;
  float* hid    = ws + 1703936;
  float* smat   = ws + 2228224;
  float* f      = ws + 2232320;
  float* wia_t  = ws + 2240512;
  float* wsa_t  = ws + 2306048;
  float* wsf_t  = ws + 2371584;
  float* vsf_t  = ws + 2633728;

  k_prep<<<1184, 256, 0, stream>>>(W_ID, V2_w, V1_ID, W_ia, W_sa, W_SF, V_SF,
                                   wbp, v2h, v2l, v1h, v1l,
                                   wia_t, wsa_t, wsf_t, vsf_t);
  k_lin<<<dim3(64, 4), 256, 0, stream>>>(h, nullptr, nullptr, v2h, v2l, V2_b,
                                         sfbuf, r_slot, nullptr, f);

  for (int it = 0; it < 3; ++it) {
    k_mid<<<128, 512, 0, stream>>>(it == 0 ? 1 : 0, smat, r_slot, c_inte,
                                   c_slot, wsf_t, vsf_t, f);
    k_lin<<<dim3(64, 4), 256, 0, stream>>>(nullptr, c_slot, f, v1h, v1l,
                                           nullptr, hid, r_slot, smat, nullptr);
    k_score<<<dim3(64, 16), 512, 0, stream>>>(hid, sfbuf, wbp, smat, f,
                                              it == 2 ? out : nullptr);
  }

  k_post<<<384, 256, 0, stream>>>(smat, r_slot, c_inte, h, wia_t, wsa_t, out);
}

// Round 13
// 301.599 us; speedup vs baseline: 3.8351x; 1.0155x over previous
//
#include <hip/hip_runtime.h>
#include <math.h>

// B=16, L=64, H=512, N_LABELS=64, ITERS=3
//
// ws layout (float offsets):
//   wbp 0 [131072] W_ID bf16 B-fragment-major
//   v1h 393216, v1l 524288 [131072 each] split-bf16 V1
//   sfbuf 655360, r_slot 1179648, hid 1703936 [524288 each]
//   smat 2228224 [4096], f 2232320 [8192]
//   wia_t 2240512, wsa_t 2306048 [65536 each]
//   wsf_t 2371584, vsf_t 2633728 [262144 each]

typedef __attribute__((ext_vector_type(8))) short bf16x8;
typedef __attribute__((ext_vector_type(4))) float f32x4;

__device__ inline short f2bf(float x) {  // RNE
  unsigned u = __float_as_uint(x);
  unsigned r = (u + 0x7fffu + ((u >> 16) & 1u)) >> 16;
  return (short)r;
}
__device__ inline float bf2f(short s) {
  return __uint_as_float(((unsigned)(unsigned short)s) << 16);
}
__device__ inline unsigned pack2(float a, float b) {  // truncating 2xbf16
  return (__float_as_uint(a) >> 16) | (__float_as_uint(b) & 0xffff0000u);
}
__device__ inline float ftanh(float x) {
  float t = __expf(2.f * x);
  return 1.f - 2.f * __builtin_amdgcn_rcpf(t + 1.f);
}
__device__ inline void split8(float4 a, float4 b, bf16x8* hi, bf16x8* lo) {
  float xs[8] = {a.x, a.y, a.z, a.w, b.x, b.y, b.z, b.w};
  bf16x8 h, l;
#pragma unroll
  for (int e = 0; e < 8; ++e) {
    short hh = f2bf(xs[e]);
    h[e] = hh;
    l[e] = f2bf(xs[e] - bf2f(hh));
  }
  *hi = h;
  *lo = l;
}

// ---- first linear (raw f32 B, split in-register) + all prep as extra planes.
// grid (64, 15): nh<4 -> sfbuf = h @ V2^T + bias (128 cols per plane... 4 planes
// x 8 ntiles); nh>=4 -> prep: pid<256 wbp pack, <512 v1 pack, <672 transposes.
__global__ __launch_bounds__(256) void k_lin1(
    const float* __restrict__ A, const float* __restrict__ rawB,
    const float* __restrict__ bias, float* __restrict__ C,
    const float* __restrict__ W_ID, const float* __restrict__ V1,
    const float* __restrict__ W_ia, const float* __restrict__ W_sa,
    const float* __restrict__ W_SF, const float* __restrict__ V_SF,
    short* __restrict__ wbp, short* __restrict__ v1h, short* __restrict__ v1l,
    float* __restrict__ wia_t, float* __restrict__ wsa_t,
    float* __restrict__ wsf_t, float* __restrict__ vsf_t,
    float* __restrict__ fzero) {
  __shared__ short Ah[2][512], Al[2][512];
  __shared__ float tile[64][65];
  const int nh = blockIdx.y;
  const int t = threadIdx.x;

  if (nh >= 4) {
    const int pid = (nh - 4) * 64 + blockIdx.x;
    if (pid < 256) {  // wbp pack, 4 elems/thread
#pragma unroll
      for (int e = 0; e < 4; ++e) {
        int idx = pid * 1024 + e * 256 + t;
        int j = idx & 7, lane = (idx >> 3) & 63;
        int ntile = (idx >> 9) & 31, kstep = idx >> 14;
        int g = ntile * 16 + (lane & 15);
        int h = kstep * 32 + (lane >> 4) * 8 + j;
        wbp[idx] = f2bf(W_ID[g * 512 + h]);
      }
    } else if (pid < 512) {  // v1 split pack
      int p = pid - 256;
#pragma unroll
      for (int e = 0; e < 4; ++e) {
        int idx = p * 1024 + e * 256 + t;
        int j = idx & 7, lane = (idx >> 3) & 63;
        int ntile = (idx >> 9) & 31, kstep = idx >> 14;
        int g = ntile * 16 + (lane & 15);
        int h = kstep * 32 + (lane >> 4) * 8 + j;
        float x = V1[g * 512 + h];
        short hi = f2bf(x);
        v1h[idx] = hi;
        v1l[idx] = f2bf(x - bf2f(hi));
      }
    } else if (pid < 672) {  // transposes
      int p = pid - 512;
      const float* tin;
      float* tout;
      int R, C2, c0, r0;
      if (p < 64) {
        tin = W_SF; tout = wsf_t; R = 512; C2 = 512;
        c0 = (p & 7) * 64; r0 = (p >> 3) * 64;
      } else if (p < 128) {
        int q = p - 64;
        tin = V_SF; tout = vsf_t; R = 512; C2 = 512;
        c0 = (q & 7) * 64; r0 = (q >> 3) * 64;
      } else if (p < 144) {
        tin = W_ia; tout = wia_t; R = 64; C2 = 1024;
        c0 = (p - 128) * 64; r0 = 0;
      } else {
        tin = W_sa; tout = wsa_t; R = 64; C2 = 1024;
        c0 = (p - 144) * 64; r0 = 0;
      }
      const int tx = t & 63, ty = t >> 6;
#pragma unroll
      for (int it2 = 0; it2 < 16; ++it2) {
        int rl = ty + it2 * 4;
        tile[rl][tx] = tin[(r0 + rl) * C2 + c0 + tx];
      }
      __syncthreads();
#pragma unroll
      for (int it2 = 0; it2 < 16; ++it2) {
        int cl = ty + it2 * 4;
        tout[(c0 + cl) * R + r0 + tx] = tile[tx][cl];
      }
    }
    return;
  }

  // ---- gemm planes (nh<4): raw f32 B, split in-register ----
  const int m0 = blockIdx.x * 16;
  if (fzero && nh == 1 && blockIdx.x < 16) {
    fzero[blockIdx.x * 512 + t] = 0.f;
    fzero[blockIdx.x * 512 + 256 + t] = 0.f;
  }
  const int w = t >> 6, lane = t & 63;
  const int lq = lane >> 4, lm = lane & 15;
  f32x4 acc[2];
#pragma unroll
  for (int c = 0; c < 2; ++c) acc[c] = (f32x4){0.f, 0.f, 0.f, 0.f};

  const int nt0 = nh * 8 + w * 2;
  const float* vb0 = rawB + (nt0 * 16 + lm) * 512 + lq * 8;
  const float* vb1 = vb0 + 16 * 512;

  const int la = t >> 2, j0 = (t & 3) * 2;
  const int m = la & 15, kk = (la >> 4) * 8 + j0;
  const float* abase = A + (m0 + m) * 512 + kk;
  float2 x = *(const float2*)abase;

  for (int ks = 0; ks < 16; ++ks) {
    const int buf = ks & 1;
    float4 q0 = *(const float4*)(vb0 + ks * 32);
    float4 q1 = *(const float4*)(vb0 + ks * 32 + 4);
    float4 p0 = *(const float4*)(vb1 + ks * 32);
    float4 p1 = *(const float4*)(vb1 + ks * 32 + 4);
    float2 xn = x;
    if (ks < 15) xn = *(const float2*)(abase + (ks + 1) * 32);
    short h0 = f2bf(x.x), h1 = f2bf(x.y);
    short l0 = f2bf(x.x - bf2f(h0)), l1 = f2bf(x.y - bf2f(h1));
    *(short2*)&Ah[buf][t * 2] = make_short2(h0, h1);
    *(short2*)&Al[buf][t * 2] = make_short2(l0, l1);
    bf16x8 b0h, b0l, b1h, b1l;
    split8(q0, q1, &b0h, &b0l);
    split8(p0, p1, &b1h, &b1l);
    __syncthreads();
    bf16x8 ah = *(const bf16x8*)&Ah[buf][lane * 8];
    bf16x8 al = *(const bf16x8*)&Al[buf][lane * 8];
    acc[0] = __builtin_amdgcn_mfma_f32_16x16x32_bf16(ah, b0h, acc[0], 0, 0, 0);
    acc[0] = __builtin_amdgcn_mfma_f32_16x16x32_bf16(al, b0h, acc[0], 0, 0, 0);
    acc[0] = __builtin_amdgcn_mfma_f32_16x16x32_bf16(ah, b0l, acc[0], 0, 0, 0);
    acc[1] = __builtin_amdgcn_mfma_f32_16x16x32_bf16(ah, b1h, acc[1], 0, 0, 0);
    acc[1] = __builtin_amdgcn_mfma_f32_16x16x32_bf16(al, b1h, acc[1], 0, 0, 0);
    acc[1] = __builtin_amdgcn_mfma_f32_16x16x32_bf16(ah, b1l, acc[1], 0, 0, 0);
    x = xn;
  }
#pragma unroll
  for (int c = 0; c < 2; ++c)
#pragma unroll
    for (int reg = 0; reg < 4; ++reg) {
      int mm = m0 + lq * 4 + reg;
      int n = (nt0 + c) * 16 + lm;
      C[mm * 512 + n] = acc[c][reg] + bias[n];
    }
}

// ---- split-precision MFMA linear (loop version, packed B) ----
// grid (64, 4); mode: A = f[b,:] (x) c_slot, nh==0 writes r_slot, zeroes smat.
__global__ __launch_bounds__(256) void k_lin(const float* __restrict__ c_slot,
                                             const float* __restrict__ f,
                                             const short* __restrict__ bh,
                                             const short* __restrict__ bl,
                                             float* __restrict__ C,
                                             float* __restrict__ rs_out,
                                             float* __restrict__ smat0) {
  __shared__ short Ah[2][512], Al[2][512];
  __shared__ float fl[512];
  const int m0 = blockIdx.x * 16;
  const int nh = blockIdx.y;
  const int t = threadIdx.x;
  if (nh == 0 && blockIdx.x < 8) {
    smat0[blockIdx.x * 512 + t] = 0.f;
    smat0[blockIdx.x * 512 + 256 + t] = 0.f;
  }
  fl[t] = f[(blockIdx.x >> 2) * 512 + t];
  fl[t + 256] = f[(blockIdx.x >> 2) * 512 + 256 + t];
  const int w = t >> 6, lane = t & 63;
  const int lq = lane >> 4, lm = lane & 15;
  f32x4 acc[2];
#pragma unroll
  for (int c = 0; c < 2; ++c) acc[c] = (f32x4){0.f, 0.f, 0.f, 0.f};

  const bf16x8* gbh = (const bf16x8*)bh + (nh * 8 + w * 2) * 64 + lane;
  const bf16x8* gbl = (const bf16x8*)bl + (nh * 8 + w * 2) * 64 + lane;

  const int la = t >> 2, j0 = (t & 3) * 2;
  const int m = la & 15, kk = (la >> 4) * 8 + j0;
  const float* abase = c_slot + (m0 + m) * 512 + kk;
  float* rbase = rs_out + (m0 + m) * 512 + kk;
  __syncthreads();  // fl ready
  float2 x = *(const float2*)abase;

  for (int ks = 0; ks < 16; ++ks) {
    const int buf = ks & 1;
    bf16x8 b0h = gbh[ks * 2048];
    bf16x8 b1h = gbh[ks * 2048 + 64];
    bf16x8 b0l = gbl[ks * 2048];
    bf16x8 b1l = gbl[ks * 2048 + 64];
    float2 xn = x;
    if (ks < 15) xn = *(const float2*)(abase + (ks + 1) * 32);
    float a0 = x.x * fl[ks * 32 + kk];
    float a1 = x.y * fl[ks * 32 + kk + 1];
    if (nh == 0) *(float2*)(rbase + ks * 32) = make_float2(a0, a1);
    short h0 = f2bf(a0), h1 = f2bf(a1);
    short l0 = f2bf(a0 - bf2f(h0)), l1 = f2bf(a1 - bf2f(h1));
    *(short2*)&Ah[buf][t * 2] = make_short2(h0, h1);
    *(short2*)&Al[buf][t * 2] = make_short2(l0, l1);
    __syncthreads();
    bf16x8 ah = *(const bf16x8*)&Ah[buf][lane * 8];
    bf16x8 al = *(const bf16x8*)&Al[buf][lane * 8];
    acc[0] = __builtin_amdgcn_mfma_f32_16x16x32_bf16(ah, b0h, acc[0], 0, 0, 0);
    acc[0] = __builtin_amdgcn_mfma_f32_16x16x32_bf16(al, b0h, acc[0], 0, 0, 0);
    acc[0] = __builtin_amdgcn_mfma_f32_16x16x32_bf16(ah, b0l, acc[0], 0, 0, 0);
    acc[1] = __builtin_amdgcn_mfma_f32_16x16x32_bf16(ah, b1h, acc[1], 0, 0, 0);
    acc[1] = __builtin_amdgcn_mfma_f32_16x16x32_bf16(al, b1h, acc[1], 0, 0, 0);
    acc[1] = __builtin_amdgcn_mfma_f32_16x16x32_bf16(ah, b1l, acc[1], 0, 0, 0);
    x = xn;
  }
#pragma unroll
  for (int c = 0; c < 2; ++c)
#pragma unroll
    for (int reg = 0; reg < 4; ++reg) {
      int mm = m0 + lq * 4 + reg;
      int n = nh * 128 + (w * 2 + c) * 16 + lm;
      C[mm * 512 + n] = acc[c][reg];
    }
}

// ---- per-iteration mid chain (unchanged from round 12) ----
__global__ __launch_bounds__(512) void k_mid(int first,
                                             const float* __restrict__ smat,
                                             const float* __restrict__ r_slot,
                                             const float* __restrict__ c_inte,
                                             const float* __restrict__ c_slot,
                                             const float* __restrict__ wsf_t,
                                             const float* __restrict__ vsf_t,
                                             float* __restrict__ f) {
  __shared__ float av[64];
  __shared__ float riv[512];
  __shared__ float red[512];
  __shared__ float tm[64], ts[64];
  const int b = blockIdx.x >> 3, hc = blockIdx.x & 7;
  const int t = threadIdx.x;
  const int hl = t & 63, kq = t >> 6;

  if (first) {
    riv[t] = c_inte[b * 512 + t];
  } else {
    if (t < 256) {
      int w = t >> 6, lane = t & 63;
      for (int r = w * 16; r < w * 16 + 16; ++r) {
        float v = smat[r * 64 + lane];
        float s = v;
        s += __shfl_xor(s, 1);
        s += __shfl_xor(s, 2);
        s += __shfl_xor(s, 4);
        s += __shfl_xor(s, 8);
        s += __shfl_xor(s, 16);
        s += __shfl_xor(s, 32);
        float d = __shfl(v, r);
        if (lane == 0) av[r] = d / s;
      }
    }
    __syncthreads();
    float a = 0.f;
    const float* rp = r_slot + b * 64 * 512 + t;
#pragma unroll 8
    for (int i = 0; i < 64; ++i) a += av[i] * rp[i * 512];
    riv[t] = a + c_inte[b * 512 + t];
  }
  __syncthreads();
  {
    const float* wp = wsf_t + hc * 64 + hl;
    float p = 0.f;
#pragma unroll 8
    for (int k = kq * 64; k < kq * 64 + 64; ++k) p += riv[k] * wp[k * 512];
    red[t] = p;
  }
  __syncthreads();
  if (t < 64) {
    float s = 0.f;
#pragma unroll
    for (int q = 0; q < 8; ++q) s += red[q * 64 + t];
    tm[t] = s;
  }
  __syncthreads();
  {
    float tmph = tm[hl];
    const float* cp = c_slot + (b * 64 + kq * 8) * 512 + hc * 64 + hl;
    float s = 0.f;
#pragma unroll
    for (int l = 0; l < 8; ++l) s += ftanh(cp[l * 512] + tmph);
    red[t] = s;
  }
  __syncthreads();
  if (t < 64) {
    float s = 0.f;
#pragma unroll
    for (int q = 0; q < 8; ++q) s += red[q * 64 + t];
    ts[t] = s;
  }
  __syncthreads();
  {
    const float* vp = vsf_t + (hc * 64) * 512 + t;
    float p = 0.f;
#pragma unroll 8
    for (int k = 0; k < 64; ++k) p += ts[k] * vp[k * 512];
    atomicAdd(&f[b * 512 + t], p);
  }
}

// ---- dominant kernel v8: whole A staged once, 1 barrier, B prefetch, with
// the first kstep's B loads hoisted above the tanh staging phase. ----
__global__ __launch_bounds__(512, 4) void k_score(const float* __restrict__ hid,
                                                  const float* __restrict__ sf,
                                                  const short* __restrict__ wbp,
                                                  float* __restrict__ smat,
                                                  float* __restrict__ fz,
                                                  float* __restrict__ oz) {
  __shared__ short As[16][2048];  // 64 KB
  __shared__ float red[8][64];
  const int i = blockIdx.x, b = blockIdx.y;
  const int t = threadIdx.x;
  if (fz && i == 0) fz[b * 512 + t] = 0.f;
  if (oz && i == 1 && b < 2) oz[b * 512 + t] = 0.f;
  const int w = t >> 6, lane = t & 63;
  const int lq = lane >> 4, lm = lane & 15;

  f32x4 acc[4][4];
#pragma unroll
  for (int r = 0; r < 4; ++r)
#pragma unroll
    for (int c = 0; c < 4; ++c) acc[r][c] = (f32x4){0.f, 0.f, 0.f, 0.f};

  const float* hrow = hid + (b * 64 + i) * 512;
  const float* sfb = sf + b * 64 * 512;

  const int fid = t >> 1, half = t & 1;
  const int am = (fid >> 6) * 16 + (fid & 15);
  const int ak = ((fid >> 4) & 3) * 8 + half * 4;
  const int aoff = fid * 8 + half * 4;

  const float* hp0 = hrow + ak;
  const float* sp0 = sfb + am * 512 + ak;

  // hoisted: first kstep's B fragments in flight during staging
  const bf16x8* gb = (const bf16x8*)wbp + (w * 4) * 64 + lane;
  bf16x8 nb0 = gb[0];
  bf16x8 nb1 = gb[64];
  bf16x8 nb2 = gb[128];
  bf16x8 nb3 = gb[192];

#pragma unroll 4
  for (int ks = 0; ks < 16; ++ks) {
    float4 hv = *(const float4*)(hp0 + ks * 32);
    float4 sv = *(const float4*)(sp0 + ks * 32);
    uint2 pk;
    pk.x = pack2(ftanh(hv.x + sv.x), ftanh(hv.y + sv.y));
    pk.y = pack2(ftanh(hv.z + sv.z), ftanh(hv.w + sv.w));
    *(uint2*)&As[ks][aoff] = pk;
  }
  __syncthreads();

  for (int ks = 0; ks < 16; ++ks) {
    bf16x8 b0 = nb0, b1 = nb1, b2 = nb2, b3 = nb3;
    if (ks < 15) {
      nb0 = gb[(ks + 1) * 2048];
      nb1 = gb[(ks + 1) * 2048 + 64];
      nb2 = gb[(ks + 1) * 2048 + 128];
      nb3 = gb[(ks + 1) * 2048 + 192];
    }
    bf16x8 af0 = *(const bf16x8*)&As[ks][(0 * 64 + lane) * 8];
    bf16x8 af1 = *(const bf16x8*)&As[ks][(1 * 64 + lane) * 8];
    bf16x8 af2 = *(const bf16x8*)&As[ks][(2 * 64 + lane) * 8];
    bf16x8 af3 = *(const bf16x8*)&As[ks][(3 * 64 + lane) * 8];
    acc[0][0] = __builtin_amdgcn_mfma_f32_16x16x32_bf16(af0, b0, acc[0][0], 0, 0, 0);
    acc[1][0] = __builtin_amdgcn_mfma_f32_16x16x32_bf16(af1, b0, acc[1][0], 0, 0, 0);
    acc[2][0] = __builtin_amdgcn_mfma_f32_16x16x32_bf16(af2, b0, acc[2][0], 0, 0, 0);
    acc[3][0] = __builtin_amdgcn_mfma_f32_16x16x32_bf16(af3, b0, acc[3][0], 0, 0, 0);
    acc[0][1] = __builtin_amdgcn_mfma_f32_16x16x32_bf16(af0, b1, acc[0][1], 0, 0, 0);
    acc[1][1] = __builtin_amdgcn_mfma_f32_16x16x32_bf16(af1, b1, acc[1][1], 0, 0, 0);
    acc[2][1] = __builtin_amdgcn_mfma_f32_16x16x32_bf16(af2, b1, acc[2][1], 0, 0, 0);
    acc[3][1] = __builtin_amdgcn_mfma_f32_16x16x32_bf16(af3, b1, acc[3][1], 0, 0, 0);
    acc[0][2] = __builtin_amdgcn_mfma_f32_16x16x32_bf16(af0, b2, acc[0][2], 0, 0, 0);
    acc[1][2] = __builtin_amdgcn_mfma_f32_16x16x32_bf16(af1, b2, acc[1][2], 0, 0, 0);
    acc[2][2] = __builtin_amdgcn_mfma_f32_16x16x32_bf16(af2, b2, acc[2][2], 0, 0, 0);
    acc[3][2] = __builtin_amdgcn_mfma_f32_16x16x32_bf16(af3, b2, acc[3][2], 0, 0, 0);
    acc[0][3] = __builtin_amdgcn_mfma_f32_16x16x32_bf16(af0, b3, acc[0][3], 0, 0, 0);
    acc[1][3] = __builtin_amdgcn_mfma_f32_16x16x32_bf16(af1, b3, acc[1][3], 0, 0, 0);
    acc[2][3] = __builtin_amdgcn_mfma_f32_16x16x32_bf16(af2, b3, acc[2][3], 0, 0, 0);
    acc[3][3] = __builtin_amdgcn_mfma_f32_16x16x32_bf16(af3, b3, acc[3][3], 0, 0, 0);
  }

#pragma unroll
  for (int r = 0; r < 4; ++r) {
#pragma unroll
    for (int reg = 0; reg < 4; ++reg) {
      float v = __expf(acc[r][0][reg]) + __expf(acc[r][1][reg]) +
                __expf(acc[r][2][reg]) + __expf(acc[r][3][reg]);
      v += __shfl_down(v, 8, 16);
      v += __shfl_down(v, 4, 16);
      v += __shfl_down(v, 2, 16);
      v += __shfl_down(v, 1, 16);
      if (lm == 0) red[w][r * 16 + lq * 4 + reg] = v;
    }
  }
  __syncthreads();
  if (t < 64) {
    float s = 0.f;
#pragma unroll
    for (int ww = 0; ww < 8; ++ww) s += red[ww][t];
    atomicAdd(&smat[i * 64 + t], s);
  }
}

// ---- post: k_slot (bx<256) + k_fin (bx>=256) merged (unchanged) ----
__global__ __launch_bounds__(256) void k_post(const float* __restrict__ smat,
                                              const float* __restrict__ r_slot,
                                              const float* __restrict__ c_inte,
                                              const float* __restrict__ h,
                                              const float* __restrict__ wia_t,
                                              const float* __restrict__ wsa_t,
                                              float* __restrict__ out) {
  __shared__ float av[64], riv[64], red[256];
  const int t = threadIdx.x;
  if (blockIdx.x < 256) {
    int idx = blockIdx.x * 256 + t;  // 65536
    int ml = idx >> 6, n = idx & 63;
    const float* x1 = h + ml * 512;
    const float* x2 = r_slot + ml * 512;
    float acc = 0.f;
    for (int k = 0; k < 512; k += 4) {
      float4 x = *(const float4*)(x1 + k);
      acc += x.x * wsa_t[k * 64 + n] + x.y * wsa_t[(k + 1) * 64 + n] +
             x.z * wsa_t[(k + 2) * 64 + n] + x.w * wsa_t[(k + 3) * 64 + n];
    }
    for (int k = 0; k < 512; k += 4) {
      float4 x = *(const float4*)(x2 + k);
      acc += x.x * wsa_t[(512 + k) * 64 + n] + x.y * wsa_t[(513 + k) * 64 + n] +
             x.z * wsa_t[(514 + k) * 64 + n] + x.w * wsa_t[(515 + k) * 64 + n];
    }
    out[1024 + idx] = acc;
  } else {
    const int bb = blockIdx.x - 256;
    const int b = bb >> 3, kc = bb & 7;
    const int w = t >> 6, lane = t & 63;
    for (int r = w * 16; r < w * 16 + 16; ++r) {
      float v = smat[r * 64 + lane];
      float s = v;
      s += __shfl_xor(s, 1);
      s += __shfl_xor(s, 2);
      s += __shfl_xor(s, 4);
      s += __shfl_xor(s, 8);
      s += __shfl_xor(s, 16);
      s += __shfl_xor(s, 32);
      float d = __shfl(v, r);
      if (lane == 0) av[r] = d / s;
    }
    __syncthreads();
    {
      const int hh = kc * 64 + lane;
      float a = 0.f;
      const float* rp = r_slot + (b * 64 + w * 16) * 512 + hh;
#pragma unroll
      for (int i = 0; i < 16; ++i) a += av[w * 16 + i] * rp[i * 512];
      red[t] = a;
    }
    __syncthreads();
    if (t < 64)
      riv[t] = red[t] + red[t + 64] + red[t + 128] + red[t + 192] +
               c_inte[b * 512 + kc * 64 + t];
    __syncthreads();
    {
      const int n = lane;
      const float* hrow = h + (b * 64 + 63) * 512 + kc * 64;
      float p = 0.f;
#pragma unroll
      for (int k = w * 16; k < w * 16 + 16; ++k) {
        p += riv[k] * wia_t[(kc * 64 + k) * 64 + n];
        p += hrow[k] * wia_t[(512 + kc * 64 + k) * 64 + n];
      }
      red[t] = p;
    }
    __syncthreads();
    if (t < 64)
      atomicAdd(&out[b * 64 + t],
                red[t] + red[t + 64] + red[t + 128] + red[t + 192]);
  }
}

extern "C" void kernel_launch(void* const* d_in, const int* in_sizes, int n_in,
                              void* d_out, int out_size, void* d_ws, size_t ws_size,
                              hipStream_t stream) {
  const float* h      = (const float*)d_in[0];
  const float* c_slot = (const float*)d_in[1];
  const float* c_inte = (const float*)d_in[2];
  const float* W_SF   = (const float*)d_in[3];
  const float* V_SF   = (const float*)d_in[4];
  const float* V1_ID  = (const float*)d_in[5];
  const float* V2_w   = (const float*)d_in[6];
  const float* V2_b   = (const float*)d_in[7];
  const float* W_ID   = (const float*)d_in[8];
  const float* W_ia   = (const float*)d_in[9];
  const float* W_sa   = (const float*)d_in[10];
  float* out = (float*)d_out;

  float* ws     = (float*)d_ws;
  short* wbp    = (short*)ws;
  short* v1h    = (short*)(ws + 393216);
  short* v1l    = (short*)(ws + 524288);
  float* sfbuf  = ws + 655360;
  float* r_slot = ws + 1179648;
  float* hid    = ws + 1703936;
  float* smat   = ws + 2228224;
  float* f      = ws + 2232320;
  float* wia_t  = ws + 2240512;
  float* wsa_t  = ws + 2306048;
  float* wsf_t  = ws + 2371584;
  float* vsf_t  = ws + 2633728;

  // sfbuf = h @ V2^T + bias (raw f32 B) + ALL prep work in extra planes.
  k_lin1<<<dim3(64, 15), 256, 0, stream>>>(h, V2_w, V2_b, sfbuf,
                                           W_ID, V1_ID, W_ia, W_sa, W_SF, V_SF,
                                           wbp, v1h, v1l,
                                           wia_t, wsa_t, wsf_t, vsf_t, f);

  for (int it = 0; it < 3; ++it) {
    k_mid<<<128, 512, 0, stream>>>(it == 0 ? 1 : 0, smat, r_slot, c_inte,
                                   c_slot, wsf_t, vsf_t, f);
    k_lin<<<dim3(64, 4), 256, 0, stream>>>(c_slot, f, v1h, v1l,
                                           hid, r_slot, smat);
    k_score<<<dim3(64, 16), 512, 0, stream>>>(hid, sfbuf, wbp, smat, f,
                                              it == 2 ? out : nullptr);
  }

  k_post<<<384, 256, 0, stream>>>(smat, r_slot, c_inte, h, wia_t, wsa_t, out);
}